// Round 1
// baseline (836.572 us; speedup 1.0000x reference)
//
#include <hip/hip_runtime.h>

#define NN 50000
#define NE 800000
#define NG 128
#define YW 1664   // 25*64 + 64 root columns

typedef unsigned int uint;
typedef unsigned short ushort;
typedef __attribute__((ext_vector_type(8))) short short8;
typedef __attribute__((ext_vector_type(4))) float f32x4;

__device__ __forceinline__ float bf2f(ushort u){ union{uint i; float f;} v; v.i=(uint)u<<16; return v.f; }
__device__ __forceinline__ ushort f2bf(float f){ union{float f; uint i;} v; v.f=f; return (ushort)((v.i + 0x7FFFu + ((v.i>>16)&1u))>>16); }

// ---------------- zero scratch that must be re-initialized every call ----------------
__global__ void zero_k(int* hist, float* pooled, int* gcnt){
    int i = blockIdx.x*blockDim.x + threadIdx.x;
    if (i < NN) hist[i] = 0;
    if (i < NG*64) pooled[i] = 0.f;
    if (i < NG) gcnt[i] = 0;
}

// ---------------- per-edge spline coefficients (4 corners) + dst histogram ----------------
__global__ void coeff_k(const float* __restrict__ pseudo, const int* __restrict__ ei,
                        float* __restrict__ w4, uint* __restrict__ idx4, int* __restrict__ hist){
    int e = blockIdx.x*blockDim.x + threadIdx.x;
    if (e >= NE) return;
    float px = pseudo[2*e]   * 4.0f;
    float py = pseudo[2*e+1] * 4.0f;
    int lx = min(max((int)floorf(px), 0), 3);
    int ly = min(max((int)floorf(py), 0), 3);
    float fx = px - (float)lx, fy = py - (float)ly;
    float w0x = 1.f-fx, w1x = fx, w0y = 1.f-fy, w1y = fy;
    int k0 = lx   + 5*ly;       // (i0,i0)
    int k1 = lx   + 5*(ly+1);   // (i0,i1)
    int k2 = lx+1 + 5*ly;       // (i1,i0)
    int k3 = lx+1 + 5*(ly+1);   // (i1,i1)
    idx4[e] = (uint)k0 | ((uint)k1<<8) | ((uint)k2<<16) | ((uint)k3<<24);
    float4 w = make_float4(w0x*w0y, w0x*w1y, w1x*w0y, w1x*w1y);
    *(float4*)(w4 + 4*(size_t)e) = w;
    atomicAdd(&hist[ei[NE + e]], 1);
}

// ---------------- exclusive scan of hist -> offs, cursor, inv_cnt ----------------
__global__ __launch_bounds__(1024) void scan_k(const int* __restrict__ hist, int* __restrict__ offs,
                                               int* __restrict__ cursor, float* __restrict__ invc){
    __shared__ int part[1024];
    int t = threadIdx.x;
    const int CH = (NN + 1023) / 1024;   // 49
    int base = t * CH;
    int lim = min(base + CH, NN);
    int s = 0;
    for (int i = base; i < lim; ++i) s += hist[i];
    part[t] = s; __syncthreads();
    for (int o = 1; o < 1024; o <<= 1){
        int v = (t >= o) ? part[t-o] : 0;
        __syncthreads();
        part[t] += v;
        __syncthreads();
    }
    int run = (t == 0) ? 0 : part[t-1];
    for (int i = base; i < lim; ++i){
        int h = hist[i];
        offs[i] = run; cursor[i] = run;
        invc[i] = 1.0f / (float)max(h, 1);
        run += h;
    }
    if (t == 1023) offs[NN] = part[1023];
}

// ---------------- counting-sort scatter: payload[pos] = {src, idx4, w0..w3, pad} (32B) ----------------
__global__ void scatter_k(const int* __restrict__ ei, const float* __restrict__ w4,
                          const uint* __restrict__ idx4, int* __restrict__ cursor, uint* __restrict__ payload){
    int e = blockIdx.x*blockDim.x + threadIdx.x;
    if (e >= NE) return;
    int dst = ei[NE + e];
    int pos = atomicAdd(&cursor[dst], 1);
    float4 w = *(const float4*)(w4 + 4*(size_t)e);
    uint4* pl = (uint4*)(payload + (size_t)pos*8);
    pl[0] = make_uint4((uint)ei[e], idx4[e], __float_as_uint(w.x), __float_as_uint(w.y));
    pl[1] = make_uint4(__float_as_uint(w.z), __float_as_uint(w.w), 0u, 0u);
}

// ---------------- pack W (+root as extra 64 cols) into MFMA B-fragment layout, bf16 ----------------
// Bp[st][ct][lane][j] = Wt[st*32 + (lane>>4)*8 + j][ct*16 + (lane&15)]
// Wt[i][k*64+o] = W[k][i][o] (k<25) ; Wt[i][1600+o] = root[i][o]
template<int IN>
__global__ void wprep_k(const float* __restrict__ W, const float* __restrict__ root, ushort* __restrict__ Bp){
    const int total = (IN/32)*104*64*8;
    int tid = blockIdx.x*blockDim.x + threadIdx.x;
    if (tid >= total) return;
    int j    = tid & 7;
    int lane = (tid >> 3) & 63;
    int ctst = tid >> 9;           // st*104 + ct
    int ct   = ctst % 104;
    int st   = ctst / 104;
    int i    = st*32 + (lane>>4)*8 + j;       // input-dim index, < IN
    int col  = ct*16 + (lane & 15);           // 0..1663
    float v;
    if (col < 1600){ int k = col >> 6; int o = col & 63; v = W[((size_t)k*IN + i)*64 + o]; }
    else           { int o = col - 1600;                 v = root[(size_t)i*64 + o]; }
    Bp[tid] = f2bf(v);
}

// ---------------- layer 1: CSR reduce with tiny W1 in LDS (in=1, out=32) ----------------
__global__ __launch_bounds__(256) void reduce1_k(const float* __restrict__ x, const uint* __restrict__ payload,
                                                 const int* __restrict__ offs, const float* __restrict__ invc,
                                                 const float* __restrict__ W1, const float* __restrict__ root1,
                                                 const float* __restrict__ b1, ushort* __restrict__ h1bf){
    __shared__ float w1s[25*32];
    for (int i = threadIdx.x; i < 25*32; i += 256) w1s[i] = W1[i];
    __syncthreads();
    int wid  = threadIdx.x >> 6;
    int lane = threadIdx.x & 63;
    int o    = lane & 31;
    int half = lane >> 5;              // half 0: corners 0,1 ; half 1: corners 2,3
    int d    = blockIdx.x*4 + wid;
    int s = offs[d], e = offs[d+1];
    float acc = 0.f;
    for (int p = s; p < e; ++p){
        const uint4* q = (const uint4*)(payload + (size_t)p*8);
        uint4 A = q[0]; uint4 B = q[1];
        uint src = A.x, idxp = A.y;
        float xs = x[src];
        int ka = half ? (int)((idxp>>16)&255) : (int)(idxp&255);
        int kb = half ? (int)(idxp>>24)       : (int)((idxp>>8)&255);
        float wa = half ? __uint_as_float(B.x) : __uint_as_float(A.z);
        float wb = half ? __uint_as_float(B.y) : __uint_as_float(A.w);
        acc += wa * xs * w1s[ka*32 + o];
        acc += wb * xs * w1s[kb*32 + o];
    }
    acc += __shfl_xor(acc, 32);
    if (half == 0){
        float val = acc*invc[d] + x[d]*root1[o] + b1[o];
        val = val > 0.f ? val : expm1f(val);
        h1bf[(size_t)d*32 + o] = f2bf(val);
    }
}

// ---------------- Y GEMM: Y[n, 1664] = h[n, IN] @ Bp   (bf16 in, f32 acc, bf16 out) ----------------
template<int IN>
__global__ __launch_bounds__(256) void gemm_y(const ushort* __restrict__ Abf, const ushort* __restrict__ Bp,
                                              ushort* __restrict__ Y){
    constexpr int ST = IN/32;
    int rt   = blockIdx.x;
    int lane = threadIdx.x & 63;
    int w    = threadIdx.x >> 6;
    int row  = rt*16 + (lane & 15);
    short8 a[ST];
    #pragma unroll
    for (int st = 0; st < ST; ++st)
        a[st] = *(const short8*)(Abf + (size_t)row*IN + st*32 + (lane>>4)*8);
    for (int ct = w*26; ct < w*26 + 26; ++ct){
        f32x4 acc = {0.f,0.f,0.f,0.f};
        #pragma unroll
        for (int st = 0; st < ST; ++st){
            short8 b = *(const short8*)(Bp + ((size_t)(st*104 + ct)*64 + lane)*8);
            acc = __builtin_amdgcn_mfma_f32_16x16x32_bf16(a[st], b, acc, 0, 0, 0);
        }
        int colb = ct*16 + (lane & 15);
        int rowb = rt*16 + (lane>>4)*4;
        #pragma unroll
        for (int r = 0; r < 4; ++r)
            Y[(size_t)(rowb + r)*YW + colb] = f2bf(acc[r]);
    }
}

// ---------------- layers 2/3: CSR reduce over gathered Y rows ----------------
// MODE 0: write h_out bf16 ; MODE 1: pool into (pooled, gcnt)
template<int MODE>
__global__ __launch_bounds__(256) void reduce_y(const ushort* __restrict__ Y, const uint* __restrict__ payload,
                                                const int* __restrict__ offs, const float* __restrict__ invc,
                                                const float* __restrict__ bias, const int* __restrict__ batch,
                                                ushort* __restrict__ hout, float* __restrict__ pooled,
                                                int* __restrict__ gcnt){
    int wid  = threadIdx.x >> 6;
    int lane = threadIdx.x & 63;
    int d    = blockIdx.x*4 + wid;
    int s = offs[d], e = offs[d+1];
    float acc = 0.f;
    for (int p = s; p < e; ++p){
        const uint4* q = (const uint4*)(payload + (size_t)p*8);
        uint4 A = q[0]; uint4 B = q[1];
        uint src = A.x, idxp = A.y;
        const ushort* yr = Y + (size_t)src*YW + lane;
        acc += __uint_as_float(A.z) * bf2f(yr[(int)( idxp      &255)*64]);
        acc += __uint_as_float(A.w) * bf2f(yr[(int)((idxp>>8 ) &255)*64]);
        acc += __uint_as_float(B.x) * bf2f(yr[(int)((idxp>>16) &255)*64]);
        acc += __uint_as_float(B.y) * bf2f(yr[(int)( idxp>>24       )*64]);
    }
    float val = acc*invc[d] + bf2f(Y[(size_t)d*YW + 1600 + lane]) + bias[lane];
    val = val > 0.f ? val : expm1f(val);
    if (MODE == 0){
        hout[(size_t)d*64 + lane] = f2bf(val);
    } else {
        int g = batch[d];
        atomicAdd(&pooled[g*64 + lane], val);
        if (lane == 0) atomicAdd(&gcnt[g], 1);
    }
}

// ---------------- head: graph mean-pool -> fc -> log_softmax ----------------
__global__ __launch_bounds__(128) void head_k(const float* __restrict__ pooled, const int* __restrict__ gcnt,
                                              const float* __restrict__ fcw, const float* __restrict__ fcb,
                                              float* __restrict__ out){
    int g = threadIdx.x;
    if (g >= NG) return;
    float inv = 1.0f / fmaxf((float)gcnt[g], 1.0f);
    float logits[10];
    #pragma unroll
    for (int c = 0; c < 10; ++c) logits[c] = fcb[c];
    for (int o = 0; o < 64; ++o){
        float m = pooled[g*64 + o] * inv;
        #pragma unroll
        for (int c = 0; c < 10; ++c) logits[c] += m * fcw[o*10 + c];
    }
    float mx = logits[0];
    #pragma unroll
    for (int c = 1; c < 10; ++c) mx = fmaxf(mx, logits[c]);
    float ssum = 0.f;
    #pragma unroll
    for (int c = 0; c < 10; ++c) ssum += expf(logits[c] - mx);
    float lse = logf(ssum) + mx;
    #pragma unroll
    for (int c = 0; c < 10; ++c) out[g*10 + c] = logits[c] - lse;
}

extern "C" void kernel_launch(void* const* d_in, const int* in_sizes, int n_in,
                              void* d_out, int out_size, void* d_ws, size_t ws_size,
                              hipStream_t stream) {
    const float* x      = (const float*)d_in[0];
    const float* pseudo = (const float*)d_in[2];
    const int*   ei     = (const int*)  d_in[3];
    const int*   batch  = (const int*)  d_in[4];
    const float* W1     = (const float*)d_in[5];
    const float* root1  = (const float*)d_in[6];
    const float* b1     = (const float*)d_in[7];
    const float* W2     = (const float*)d_in[8];
    const float* root2  = (const float*)d_in[9];
    const float* b2     = (const float*)d_in[10];
    const float* W3     = (const float*)d_in[11];
    const float* root3  = (const float*)d_in[12];
    const float* b3     = (const float*)d_in[13];
    const float* fcw    = (const float*)d_in[14];
    const float* fcb    = (const float*)d_in[15];
    float* out = (float*)d_out;

    char* ws = (char*)d_ws;
    size_t off = 0;
    auto alloc = [&](size_t bytes)->char*{ char* p = ws + off; off += (bytes + 255) / 256 * 256; return p; };
    ushort* Y      = (ushort*)alloc((size_t)NN*YW*2);        // 166.4 MB, reused for layer2 & layer3
    float*  w4     = (float*) alloc((size_t)NE*16);
    uint*   idx4   = (uint*)  alloc((size_t)NE*4);
    uint*   payload= (uint*)  alloc((size_t)NE*32);
    ushort* h1bf   = (ushort*)alloc((size_t)NN*32*2);
    ushort* h2bf   = (ushort*)alloc((size_t)NN*64*2);
    int*    hist   = (int*)   alloc((size_t)NN*4);
    int*    offs   = (int*)   alloc((size_t)(NN+1)*4);
    int*    cursor = (int*)   alloc((size_t)NN*4);
    float*  invc   = (float*) alloc((size_t)NN*4);
    ushort* Bp2    = (ushort*)alloc((size_t)104*64*8*2);
    ushort* Bp3    = (ushort*)alloc((size_t)2*104*64*8*2);
    float*  pooled = (float*) alloc((size_t)NG*64*4);
    int*    gcnt   = (int*)   alloc((size_t)NG*4);
    (void)ws_size; (void)in_sizes; (void)n_in; (void)out_size;

    zero_k   <<<(NN+255)/256, 256, 0, stream>>>(hist, pooled, gcnt);
    coeff_k  <<<(NE+255)/256, 256, 0, stream>>>(pseudo, ei, w4, idx4, hist);
    scan_k   <<<1, 1024, 0, stream>>>(hist, offs, cursor, invc);
    scatter_k<<<(NE+255)/256, 256, 0, stream>>>(ei, w4, idx4, cursor, payload);
    wprep_k<32><<<(104*64*8 + 255)/256, 256, 0, stream>>>(W2, root2, Bp2);
    wprep_k<64><<<(2*104*64*8 + 255)/256, 256, 0, stream>>>(W3, root3, Bp3);
    reduce1_k<<<NN/4, 256, 0, stream>>>(x, payload, offs, invc, W1, root1, b1, h1bf);
    gemm_y<32><<<NN/16, 256, 0, stream>>>(h1bf, Bp2, Y);
    reduce_y<0><<<NN/4, 256, 0, stream>>>(Y, payload, offs, invc, b2, batch, h2bf, pooled, gcnt);
    gemm_y<64><<<NN/16, 256, 0, stream>>>(h2bf, Bp3, Y);
    reduce_y<1><<<NN/4, 256, 0, stream>>>(Y, payload, offs, invc, b3, batch, h2bf, pooled, gcnt);
    head_k   <<<1, 128, 0, stream>>>(pooled, gcnt, fcw, fcb, out);
}

// Round 2
// 769.523 us; speedup vs baseline: 1.0871x; 1.0871x over previous
//
#include <hip/hip_runtime.h>

#define NN 50000
#define NPAD 50048
#define NE 800000
#define NG 128

typedef unsigned int uint;
typedef unsigned short ushort;
typedef __attribute__((ext_vector_type(8))) short short8;
typedef __attribute__((ext_vector_type(4))) float f32x4;

__device__ __forceinline__ float bf2f(ushort u){ union{uint i; float f;} v; v.i=(uint)u<<16; return v.f; }
__device__ __forceinline__ ushort f2bf(float f){ union{float f; uint i;} v; v.f=f; return (ushort)((v.i + 0x7FFFu + ((v.i>>16)&1u))>>16); }

// ---------------- zero scratch re-initialized every call ----------------
__global__ void zero_k(int* hist, float* pooled, int* gcnt){
    int i = blockIdx.x*blockDim.x + threadIdx.x;
    if (i < NN) hist[i] = 0;
    if (i < NG*64) pooled[i] = 0.f;
    if (i < NG) gcnt[i] = 0;
}

// ---------------- per-edge data {src|lx|ly, fx, fy} + dst histogram ----------------
__global__ void coeff_k(const float* __restrict__ pseudo, const int* __restrict__ ei,
                        uint4* __restrict__ edata, int* __restrict__ hist){
    int e = blockIdx.x*blockDim.x + threadIdx.x;
    if (e >= NE) return;
    float2 ps = *(const float2*)(pseudo + 2*(size_t)e);
    float px = ps.x * 4.0f, py = ps.y * 4.0f;
    int lx = min(max((int)floorf(px), 0), 3);
    int ly = min(max((int)floorf(py), 0), 3);
    float fx = px - (float)lx, fy = py - (float)ly;
    uint meta = (uint)ei[e] | ((uint)lx<<16) | ((uint)ly<<18);   // src < 65536
    edata[e] = make_uint4(meta, __float_as_uint(fx), __float_as_uint(fy), 0u);
    atomicAdd(&hist[ei[NE + e]], 1);
}

// ---------------- exclusive scan of hist -> offs, cursor, inv_cnt ----------------
__global__ __launch_bounds__(1024) void scan_k(const int* __restrict__ hist, int* __restrict__ offs,
                                               int* __restrict__ cursor, float* __restrict__ invc){
    __shared__ int part[1024];
    int t = threadIdx.x;
    const int CH = (NN + 1023) / 1024;
    int base = t * CH;
    int lim = min(base + CH, NN);
    int s = 0;
    for (int i = base; i < lim; ++i) s += hist[i];
    part[t] = s; __syncthreads();
    for (int o = 1; o < 1024; o <<= 1){
        int v = (t >= o) ? part[t-o] : 0;
        __syncthreads();
        part[t] += v;
        __syncthreads();
    }
    int run = (t == 0) ? 0 : part[t-1];
    for (int i = base; i < lim; ++i){
        int h = hist[i];
        offs[i] = run; cursor[i] = run;
        invc[i] = 1.0f / (float)max(h, 1);
        run += h;
    }
    if (t == 1023) offs[NN] = part[1023];
}

// ---------------- counting sort: payload[pos] = edata[e] (16B) ----------------
__global__ void scatter_k(const int* __restrict__ ei, const uint4* __restrict__ edata,
                          int* __restrict__ cursor, uint4* __restrict__ payload){
    int e = blockIdx.x*blockDim.x + threadIdx.x;
    if (e >= NE) return;
    int dst = ei[NE + e];
    int pos = atomicAdd(&cursor[dst], 1);
    payload[pos] = edata[e];
}

// ---------------- pack [Wflat;root] into MFMA B-fragment layout, bf16 ----------------
// Bp[(kt*4+ct)*512 + lane*8 + j] = Bmat[kt*32 + (lane>>4)*8 + j][ct*16 + (lane&15)]
// Bmat rows kk<25*IN: W[kk/IN][kk%IN][col]; rows >=: root[kk-25*IN][col]
template<int IN>
__global__ void wprep_k(const float* __restrict__ W, const float* __restrict__ root, ushort* __restrict__ Bp){
    const int total = 26*IN*64;
    int tid = blockIdx.x*blockDim.x + threadIdx.x;
    if (tid >= total) return;
    int j    = tid & 7;
    int lane = (tid >> 3) & 63;
    int ctkt = tid >> 9;
    int ct   = ctkt & 3;
    int kt   = ctkt >> 2;
    int kk   = kt*32 + (lane>>4)*8 + j;
    int col  = ct*16 + (lane & 15);
    float v;
    if (kk < 25*IN){ int k = kk / IN; int i = kk % IN; v = W[((size_t)k*IN + i)*64 + col]; }
    else           { v = root[(size_t)(kk - 25*IN)*64 + col]; }
    Bp[tid] = f2bf(v);
}

// ---------------- layer 1: CSR reduce with tiny W1 in LDS (in=1, out=32) ----------------
__global__ __launch_bounds__(256) void reduce1_k(const float* __restrict__ x, const uint4* __restrict__ payload,
                                                 const int* __restrict__ offs, const float* __restrict__ invc,
                                                 const float* __restrict__ W1, const float* __restrict__ root1,
                                                 const float* __restrict__ b1, ushort* __restrict__ h1bf){
    __shared__ float w1s[25*32];
    for (int i = threadIdx.x; i < 25*32; i += 256) w1s[i] = W1[i];
    __syncthreads();
    int wid  = threadIdx.x >> 6;
    int lane = threadIdx.x & 63;
    int o    = lane & 31;
    int half = lane >> 5;
    int d    = blockIdx.x*4 + wid;
    int s = offs[d], e = offs[d+1];
    float acc = 0.f;
    for (int p = s; p < e; ++p){
        uint4 pl = payload[p];
        uint meta = pl.x;
        int src = meta & 0xFFFF;
        int lx = (meta>>16)&3, ly = (meta>>18)&3;
        float fx = __uint_as_float(pl.y), fy = __uint_as_float(pl.z);
        float xs = x[src];
        float gx = 1.f - fx, gy = 1.f - fy;
        int ka = ly*5 + lx + half;           // half0: (lx,ly)  half1: (lx+1,ly)
        float wa = half ? fx*gy : gx*gy;
        float wb = half ? fx*fy : gx*fy;     // y-neighbor weights
        acc += (wa*w1s[ka*32 + o] + wb*w1s[(ka+5)*32 + o]) * xs;
    }
    acc += __shfl_xor(acc, 32);
    if (half == 0){
        float val = acc*invc[d] + x[d]*root1[o] + b1[o];
        val = val > 0.f ? val : expm1f(val);
        h1bf[(size_t)d*32 + o] = f2bf(val);
    }
}

// ---------------- phase A: coefficient-space accumulate S in LDS, emit A=[S*invc | h] bf16 ----------------
template<int IN>
__global__ __launch_bounds__(256) void reduceS(const ushort* __restrict__ hin, const uint4* __restrict__ payload,
                                               const int* __restrict__ offs, const float* __restrict__ invc,
                                               ushort* __restrict__ A){
    constexpr int AW = 26*IN;
    __shared__ float S[4][25*IN];
    int wid = threadIdx.x >> 6, lane = threadIdx.x & 63;
    int d = blockIdx.x*4 + wid;
    float* Sw = S[wid];
    for (int i = lane; i < 25*IN; i += 64) Sw[i] = 0.f;
    int s = offs[d], e = offs[d+1];
    int li = lane & (IN-1);
    bool act = (IN == 64) || (lane < IN);
    for (int p = s; p < e; ++p){
        uint4 pl = payload[p];
        uint meta = pl.x;
        int src = meta & 0xFFFF;
        int lx = (meta>>16)&3, ly = (meta>>18)&3;
        float fx = __uint_as_float(pl.y), fy = __uint_as_float(pl.z);
        float gx = 1.f - fx, gy = 1.f - fy;
        if (act){
            float xs = bf2f(hin[(size_t)src*IN + li]);
            int b00 = (ly*5 + lx)*IN + li;
            Sw[b00]        += gx*gy*xs;
            Sw[b00+IN]     += fx*gy*xs;
            Sw[b00+5*IN]   += gx*fy*xs;
            Sw[b00+6*IN]   += fx*fy*xs;
        }
    }
    float ic = invc[d];
    size_t ab = (size_t)d*AW;
    for (int i = lane; i < 25*IN; i += 64) A[ab + i] = f2bf(Sw[i]*ic);
    for (int i = lane; i < IN; i += 64)   A[ab + 25*IN + i] = hin[(size_t)d*IN + i];
}

// ---------------- phase B: h_out = elu(A @ Bp + bias); MODE1 pools instead of storing ----------------
template<int KT, int MODE>
__global__ __launch_bounds__(256) void gemmS(const ushort* __restrict__ A, const ushort* __restrict__ Bp,
                                             const float* __restrict__ bias, const int* __restrict__ batch,
                                             ushort* __restrict__ hout, float* __restrict__ pooled,
                                             int* __restrict__ gcnt){
    const int AW = KT*32;
    int lane = threadIdx.x & 63, w = threadIdx.x >> 6;
    int rt = blockIdx.x*64 + w*16;
    int row = rt + (lane & 15);
    size_t abase = (size_t)row*AW + (lane>>4)*8;
    f32x4 acc0 = {0,0,0,0}, acc1 = acc0, acc2 = acc0, acc3 = acc0;
    for (int kt = 0; kt < KT; ++kt){
        short8 a = *(const short8*)(A + abase + kt*32);
        const ushort* bb = Bp + (size_t)kt*2048 + lane*8;
        acc0 = __builtin_amdgcn_mfma_f32_16x16x32_bf16(a, *(const short8*)(bb),      acc0, 0, 0, 0);
        acc1 = __builtin_amdgcn_mfma_f32_16x16x32_bf16(a, *(const short8*)(bb+512),  acc1, 0, 0, 0);
        acc2 = __builtin_amdgcn_mfma_f32_16x16x32_bf16(a, *(const short8*)(bb+1024), acc2, 0, 0, 0);
        acc3 = __builtin_amdgcn_mfma_f32_16x16x32_bf16(a, *(const short8*)(bb+1536), acc3, 0, 0, 0);
    }
    int colb = lane & 15;
    int r0 = rt + (lane>>4)*4;
#define EPI(ACC, CT) { \
    int col = (CT)*16 + colb; float bs = bias[col]; \
    _Pragma("unroll") \
    for (int r = 0; r < 4; ++r){ \
        int rr = r0 + r; \
        if (rr < NN){ \
            float val = ACC[r] + bs; \
            val = val > 0.f ? val : expm1f(val); \
            if (MODE == 0) hout[(size_t)rr*64 + col] = f2bf(val); \
            else { \
                atomicAdd(&pooled[batch[rr]*64 + col], val); \
                if ((CT) == 0 && colb == 0) atomicAdd(&gcnt[batch[rr]], 1); \
            } \
        } \
    } }
    EPI(acc0, 0) EPI(acc1, 1) EPI(acc2, 2) EPI(acc3, 3)
#undef EPI
}

// ---------------- head: graph mean-pool -> fc -> log_softmax ----------------
__global__ __launch_bounds__(128) void head_k(const float* __restrict__ pooled, const int* __restrict__ gcnt,
                                              const float* __restrict__ fcw, const float* __restrict__ fcb,
                                              float* __restrict__ out){
    int g = threadIdx.x;
    if (g >= NG) return;
    float inv = 1.0f / fmaxf((float)gcnt[g], 1.0f);
    float logits[10];
    #pragma unroll
    for (int c = 0; c < 10; ++c) logits[c] = fcb[c];
    for (int o = 0; o < 64; ++o){
        float m = pooled[g*64 + o] * inv;
        #pragma unroll
        for (int c = 0; c < 10; ++c) logits[c] += m * fcw[o*10 + c];
    }
    float mx = logits[0];
    #pragma unroll
    for (int c = 1; c < 10; ++c) mx = fmaxf(mx, logits[c]);
    float ssum = 0.f;
    #pragma unroll
    for (int c = 0; c < 10; ++c) ssum += expf(logits[c] - mx);
    float lse = logf(ssum) + mx;
    #pragma unroll
    for (int c = 0; c < 10; ++c) out[g*10 + c] = logits[c] - lse;
}

extern "C" void kernel_launch(void* const* d_in, const int* in_sizes, int n_in,
                              void* d_out, int out_size, void* d_ws, size_t ws_size,
                              hipStream_t stream) {
    const float* x      = (const float*)d_in[0];
    const float* pseudo = (const float*)d_in[2];
    const int*   ei     = (const int*)  d_in[3];
    const int*   batch  = (const int*)  d_in[4];
    const float* W1     = (const float*)d_in[5];
    const float* root1  = (const float*)d_in[6];
    const float* b1     = (const float*)d_in[7];
    const float* W2     = (const float*)d_in[8];
    const float* root2  = (const float*)d_in[9];
    const float* b2     = (const float*)d_in[10];
    const float* W3     = (const float*)d_in[11];
    const float* root3  = (const float*)d_in[12];
    const float* b3     = (const float*)d_in[13];
    const float* fcw    = (const float*)d_in[14];
    const float* fcb    = (const float*)d_in[15];
    float* out = (float*)d_out;

    char* ws = (char*)d_ws;
    size_t off = 0;
    auto alloc = [&](size_t bytes)->char*{ char* p = ws + off; off += (bytes + 255) / 256 * 256; return p; };
    ushort* Abuf   = (ushort*)alloc((size_t)NPAD*1664*2);   // 166.6 MB, shared by layer2 (832-wide) & layer3 (1664-wide)
    uint4*  edata  = (uint4*) alloc((size_t)NE*16);
    uint4*  payload= (uint4*) alloc((size_t)NE*16);
    ushort* h1bf   = (ushort*)alloc((size_t)NN*32*2);
    ushort* h2bf   = (ushort*)alloc((size_t)NN*64*2);
    int*    hist   = (int*)   alloc((size_t)NN*4);
    int*    offs   = (int*)   alloc((size_t)(NN+1)*4);
    int*    cursor = (int*)   alloc((size_t)NN*4);
    float*  invc   = (float*) alloc((size_t)NN*4);
    ushort* Bp2    = (ushort*)alloc((size_t)26*2048*2);
    ushort* Bp3    = (ushort*)alloc((size_t)52*2048*2);
    float*  pooled = (float*) alloc((size_t)NG*64*4);
    int*    gcnt   = (int*)   alloc((size_t)NG*4);
    (void)ws_size; (void)in_sizes; (void)n_in; (void)out_size;

    zero_k   <<<(NN+255)/256, 256, 0, stream>>>(hist, pooled, gcnt);
    coeff_k  <<<(NE+255)/256, 256, 0, stream>>>(pseudo, ei, edata, hist);
    scan_k   <<<1, 1024, 0, stream>>>(hist, offs, cursor, invc);
    scatter_k<<<(NE+255)/256, 256, 0, stream>>>(ei, edata, cursor, payload);
    wprep_k<32><<<(26*32*64 + 255)/256, 256, 0, stream>>>(W2, root2, Bp2);
    wprep_k<64><<<(26*64*64 + 255)/256, 256, 0, stream>>>(W3, root3, Bp3);
    reduce1_k<<<NN/4, 256, 0, stream>>>(x, payload, offs, invc, W1, root1, b1, h1bf);
    reduceS<32><<<NN/4, 256, 0, stream>>>(h1bf, payload, offs, invc, Abuf);
    gemmS<26,0><<<NPAD/64, 256, 0, stream>>>(Abuf, Bp2, b2, batch, h2bf, pooled, gcnt);
    reduceS<64><<<NN/4, 256, 0, stream>>>(h2bf, payload, offs, invc, Abuf);
    gemmS<52,1><<<NPAD/64, 256, 0, stream>>>(Abuf, Bp3, b3, batch, h2bf, pooled, gcnt);
    head_k   <<<1, 128, 0, stream>>>(pooled, gcnt, fcw, fcb, out);
}

// Round 3
// 761.590 us; speedup vs baseline: 1.0985x; 1.0104x over previous
//
#include <hip/hip_runtime.h>

#define NN 50000
#define NPAD 50048
#define NE 800000
#define NG 128

typedef unsigned int uint;
typedef unsigned short ushort;
typedef __attribute__((ext_vector_type(8))) short short8;
typedef __attribute__((ext_vector_type(4))) float f32x4;

__device__ __forceinline__ float bf2f(ushort u){ union{uint i; float f;} v; v.i=(uint)u<<16; return v.f; }
__device__ __forceinline__ ushort f2bf(float f){ union{float f; uint i;} v; v.f=f; return (ushort)((v.i + 0x7FFFu + ((v.i>>16)&1u))>>16); }

// ---------------- zero scratch re-initialized every call ----------------
__global__ void zero_k(int* hist, float* pooled, int* gcnt){
    int i = blockIdx.x*blockDim.x + threadIdx.x;
    if (i < NN) hist[i] = 0;
    if (i < NG*64) pooled[i] = 0.f;
    if (i < NG) gcnt[i] = 0;
}

// ---------------- per-edge data {src|lx|ly, fx, fy} + dst histogram ----------------
__global__ void coeff_k(const float* __restrict__ pseudo, const int* __restrict__ ei,
                        uint4* __restrict__ edata, int* __restrict__ hist){
    int e = blockIdx.x*blockDim.x + threadIdx.x;
    if (e >= NE) return;
    float2 ps = *(const float2*)(pseudo + 2*(size_t)e);
    float px = ps.x * 4.0f, py = ps.y * 4.0f;
    int lx = min(max((int)floorf(px), 0), 3);
    int ly = min(max((int)floorf(py), 0), 3);
    float fx = px - (float)lx, fy = py - (float)ly;
    uint meta = (uint)ei[e] | ((uint)lx<<16) | ((uint)ly<<18);   // src < 65536
    edata[e] = make_uint4(meta, __float_as_uint(fx), __float_as_uint(fy), 0u);
    atomicAdd(&hist[ei[NE + e]], 1);
}

// ---------------- exclusive scan of hist -> offs, cursor, inv_cnt ----------------
__global__ __launch_bounds__(1024) void scan_k(const int* __restrict__ hist, int* __restrict__ offs,
                                               int* __restrict__ cursor, float* __restrict__ invc){
    __shared__ int part[1024];
    int t = threadIdx.x;
    const int CH = (NN + 1023) / 1024;
    int base = t * CH;
    int lim = min(base + CH, NN);
    int s = 0;
    for (int i = base; i < lim; ++i) s += hist[i];
    part[t] = s; __syncthreads();
    for (int o = 1; o < 1024; o <<= 1){
        int v = (t >= o) ? part[t-o] : 0;
        __syncthreads();
        part[t] += v;
        __syncthreads();
    }
    int run = (t == 0) ? 0 : part[t-1];
    for (int i = base; i < lim; ++i){
        int h = hist[i];
        offs[i] = run; cursor[i] = run;
        invc[i] = 1.0f / (float)max(h, 1);
        run += h;
    }
    if (t == 1023) offs[NN] = part[1023];
}

// ---------------- counting sort: payload[pos] = edata[e] (16B) ----------------
__global__ void scatter_k(const int* __restrict__ ei, const uint4* __restrict__ edata,
                          int* __restrict__ cursor, uint4* __restrict__ payload){
    int e = blockIdx.x*blockDim.x + threadIdx.x;
    if (e >= NE) return;
    int dst = ei[NE + e];
    int pos = atomicAdd(&cursor[dst], 1);
    payload[pos] = edata[e];
}

// ---------------- pack [Wflat;root] into MFMA B-fragment layout, bf16 ----------------
template<int IN>
__global__ void wprep_k(const float* __restrict__ W, const float* __restrict__ root, ushort* __restrict__ Bp){
    const int total = 26*IN*64;
    int tid = blockIdx.x*blockDim.x + threadIdx.x;
    if (tid >= total) return;
    int j    = tid & 7;
    int lane = (tid >> 3) & 63;
    int ctkt = tid >> 9;
    int ct   = ctkt & 3;
    int kt   = ctkt >> 2;
    int kk   = kt*32 + (lane>>4)*8 + j;
    int col  = ct*16 + (lane & 15);
    float v;
    if (kk < 25*IN){ int k = kk / IN; int i = kk % IN; v = W[((size_t)k*IN + i)*64 + col]; }
    else           { v = root[(size_t)(kk - 25*IN)*64 + col]; }
    Bp[tid] = f2bf(v);
}

// ---------------- layer 1: CSR reduce with tiny W1 in LDS (in=1, out=32) ----------------
__global__ __launch_bounds__(256) void reduce1_k(const float* __restrict__ x, const uint4* __restrict__ payload,
                                                 const int* __restrict__ offs, const float* __restrict__ invc,
                                                 const float* __restrict__ W1, const float* __restrict__ root1,
                                                 const float* __restrict__ b1, ushort* __restrict__ h1bf){
    __shared__ float w1s[25*32];
    for (int i = threadIdx.x; i < 25*32; i += 256) w1s[i] = W1[i];
    __syncthreads();
    int wid  = threadIdx.x >> 6;
    int lane = threadIdx.x & 63;
    int o    = lane & 31;
    int half = lane >> 5;
    int d    = blockIdx.x*4 + wid;
    int s = offs[d], e = offs[d+1];
    float acc = 0.f;
#define EDGE1(PL, XS) { uint meta = (PL).x; \
    int lx = (meta>>16)&3, ly = (meta>>18)&3; \
    float fx = __uint_as_float((PL).y), fy = __uint_as_float((PL).z); \
    float gx = 1.f - fx, gy = 1.f - fy; \
    int ka = ly*5 + lx + half; \
    float wa = half ? fx*gy : gx*gy; \
    float wb = half ? fx*fy : gx*fy; \
    acc += (wa*w1s[ka*32 + o] + wb*w1s[(ka+5)*32 + o]) * (XS); }
    int p = s;
    for (; p + 2 <= e; p += 2){
        uint4 A0 = payload[p], A1 = payload[p+1];
        float x0 = x[A0.x & 0xFFFF];
        float x1 = x[A1.x & 0xFFFF];
        EDGE1(A0, x0) EDGE1(A1, x1)
    }
    if (p < e){
        uint4 A0 = payload[p];
        float x0 = x[A0.x & 0xFFFF];
        EDGE1(A0, x0)
    }
#undef EDGE1
    acc += __shfl_xor(acc, 32);
    if (half == 0){
        float val = acc*invc[d] + x[d]*root1[o] + b1[o];
        val = val > 0.f ? val : expm1f(val);
        h1bf[(size_t)d*32 + o] = f2bf(val);
    }
}

// ---------------- phase A: coefficient-space accumulate S in LDS, emit A=[S*invc | h] bf16 ----------------
template<int IN>
__global__ __launch_bounds__(256) void reduceS(const ushort* __restrict__ hin, const uint4* __restrict__ payload,
                                               const int* __restrict__ offs, const float* __restrict__ invc,
                                               ushort* __restrict__ A){
    constexpr int AW = 26*IN;
    __shared__ float S[4][25*IN];
    int wid = threadIdx.x >> 6, lane = threadIdx.x & 63;
    int d = blockIdx.x*4 + wid;
    float* Sw = S[wid];
    for (int i = lane; i < 25*IN; i += 64) Sw[i] = 0.f;
    int s = offs[d], e = offs[d+1];
    int li = lane & (IN-1);
    bool act = (IN == 64) || (lane < IN);
#define EDGES(PL, XS) { uint meta = (PL).x; \
    int lx = (meta>>16)&3, ly = (meta>>18)&3; \
    float fx = __uint_as_float((PL).y), fy = __uint_as_float((PL).z); \
    float gx = 1.f - fx, gy = 1.f - fy; \
    int b00 = (ly*5 + lx)*IN + li; \
    Sw[b00]      += gx*gy*(XS); \
    Sw[b00+IN]   += fx*gy*(XS); \
    Sw[b00+5*IN] += gx*fy*(XS); \
    Sw[b00+6*IN] += fx*fy*(XS); }
    int p = s;
    for (; p + 2 <= e; p += 2){
        uint4 A0 = payload[p], A1 = payload[p+1];
        float x0 = act ? bf2f(hin[(size_t)(A0.x & 0xFFFF)*IN + li]) : 0.f;
        float x1 = act ? bf2f(hin[(size_t)(A1.x & 0xFFFF)*IN + li]) : 0.f;
        if (act){ EDGES(A0, x0) EDGES(A1, x1) }
    }
    if (p < e){
        uint4 A0 = payload[p];
        if (act){
            float x0 = bf2f(hin[(size_t)(A0.x & 0xFFFF)*IN + li]);
            EDGES(A0, x0)
        }
    }
#undef EDGES
    float ic = invc[d];
    size_t ab = (size_t)d*AW;
    for (int i = lane; i < 25*IN; i += 64) A[ab + i] = f2bf(Sw[i]*ic);
    for (int i = lane; i < IN; i += 64)   A[ab + 25*IN + i] = hin[(size_t)d*IN + i];
}

// ---------------- phase B: h_out = elu(A @ Bp + bias); MODE1 pools instead of storing ----------------
// 16 rows/block, wave w owns column-tile ct=w (16 cols); 1 A-load + 1 B-load + 1 MFMA per kt.
template<int KT, int MODE>
__global__ __launch_bounds__(256, 8) void gemmS(const ushort* __restrict__ A, const ushort* __restrict__ Bp,
                                                const float* __restrict__ bias, const int* __restrict__ batch,
                                                ushort* __restrict__ hout, float* __restrict__ pooled,
                                                int* __restrict__ gcnt){
    const int AW = KT*32;
    int lane = threadIdx.x & 63, w = threadIdx.x >> 6;
    int rt = blockIdx.x*16;
    int row = rt + (lane & 15);
    size_t abase = (size_t)row*AW + (lane>>4)*8;
    const ushort* bbase = Bp + (size_t)w*512 + (size_t)lane*8;
    f32x4 acc = {0,0,0,0};
    #pragma unroll
    for (int kt = 0; kt < KT; ++kt){
        short8 a = *(const short8*)(A + abase + kt*32);
        short8 b = *(const short8*)(bbase + (size_t)kt*2048);
        acc = __builtin_amdgcn_mfma_f32_16x16x32_bf16(a, b, acc, 0, 0, 0);
    }
    int colb = lane & 15;
    int col  = w*16 + colb;
    float bs = bias[col];
    int r0 = rt + (lane>>4)*4;
    #pragma unroll
    for (int r = 0; r < 4; ++r){
        int rr = r0 + r;
        if (rr < NN){
            float val = acc[r] + bs;
            val = val > 0.f ? val : expm1f(val);
            if (MODE == 0){
                hout[(size_t)rr*64 + col] = f2bf(val);
            } else {
                int g = batch[rr];
                atomicAdd(&pooled[g*64 + col], val);
                if (col == 0) atomicAdd(&gcnt[g], 1);
            }
        }
    }
}

// ---------------- head: graph mean-pool -> fc -> log_softmax ----------------
__global__ __launch_bounds__(128) void head_k(const float* __restrict__ pooled, const int* __restrict__ gcnt,
                                              const float* __restrict__ fcw, const float* __restrict__ fcb,
                                              float* __restrict__ out){
    int g = threadIdx.x;
    if (g >= NG) return;
    float inv = 1.0f / fmaxf((float)gcnt[g], 1.0f);
    float logits[10];
    #pragma unroll
    for (int c = 0; c < 10; ++c) logits[c] = fcb[c];
    for (int o = 0; o < 64; ++o){
        float m = pooled[g*64 + o] * inv;
        #pragma unroll
        for (int c = 0; c < 10; ++c) logits[c] += m * fcw[o*10 + c];
    }
    float mx = logits[0];
    #pragma unroll
    for (int c = 1; c < 10; ++c) mx = fmaxf(mx, logits[c]);
    float ssum = 0.f;
    #pragma unroll
    for (int c = 0; c < 10; ++c) ssum += expf(logits[c] - mx);
    float lse = logf(ssum) + mx;
    #pragma unroll
    for (int c = 0; c < 10; ++c) out[g*10 + c] = logits[c] - lse;
}

extern "C" void kernel_launch(void* const* d_in, const int* in_sizes, int n_in,
                              void* d_out, int out_size, void* d_ws, size_t ws_size,
                              hipStream_t stream) {
    const float* x      = (const float*)d_in[0];
    const float* pseudo = (const float*)d_in[2];
    const int*   ei     = (const int*)  d_in[3];
    const int*   batch  = (const int*)  d_in[4];
    const float* W1     = (const float*)d_in[5];
    const float* root1  = (const float*)d_in[6];
    const float* b1     = (const float*)d_in[7];
    const float* W2     = (const float*)d_in[8];
    const float* root2  = (const float*)d_in[9];
    const float* b2     = (const float*)d_in[10];
    const float* W3     = (const float*)d_in[11];
    const float* root3  = (const float*)d_in[12];
    const float* b3     = (const float*)d_in[13];
    const float* fcw    = (const float*)d_in[14];
    const float* fcb    = (const float*)d_in[15];
    float* out = (float*)d_out;

    char* ws = (char*)d_ws;
    size_t off = 0;
    auto alloc = [&](size_t bytes)->char*{ char* p = ws + off; off += (bytes + 255) / 256 * 256; return p; };
    ushort* Abuf   = (ushort*)alloc((size_t)NPAD*1664*2);   // shared by layer2 (832-wide) & layer3 (1664-wide)
    uint4*  edata  = (uint4*) alloc((size_t)NE*16);
    uint4*  payload= (uint4*) alloc((size_t)NE*16);
    ushort* h1bf   = (ushort*)alloc((size_t)NN*32*2);
    ushort* h2bf   = (ushort*)alloc((size_t)NN*64*2);
    int*    hist   = (int*)   alloc((size_t)NN*4);
    int*    offs   = (int*)   alloc((size_t)(NN+1)*4);
    int*    cursor = (int*)   alloc((size_t)NN*4);
    float*  invc   = (float*) alloc((size_t)NN*4);
    ushort* Bp2    = (ushort*)alloc((size_t)26*2048*2);
    ushort* Bp3    = (ushort*)alloc((size_t)52*2048*2);
    float*  pooled = (float*) alloc((size_t)NG*64*4);
    int*    gcnt   = (int*)   alloc((size_t)NG*4);
    (void)ws_size; (void)in_sizes; (void)n_in; (void)out_size;

    zero_k   <<<(NN+255)/256, 256, 0, stream>>>(hist, pooled, gcnt);
    coeff_k  <<<(NE+255)/256, 256, 0, stream>>>(pseudo, ei, edata, hist);
    scan_k   <<<1, 1024, 0, stream>>>(hist, offs, cursor, invc);
    scatter_k<<<(NE+255)/256, 256, 0, stream>>>(ei, edata, cursor, payload);
    wprep_k<32><<<(26*32*64 + 255)/256, 256, 0, stream>>>(W2, root2, Bp2);
    wprep_k<64><<<(26*64*64 + 255)/256, 256, 0, stream>>>(W3, root3, Bp3);
    reduce1_k<<<NN/4, 256, 0, stream>>>(x, payload, offs, invc, W1, root1, b1, h1bf);
    reduceS<32><<<NN/4, 256, 0, stream>>>(h1bf, payload, offs, invc, Abuf);
    gemmS<26,0><<<NPAD/16, 256, 0, stream>>>(Abuf, Bp2, b2, batch, h2bf, pooled, gcnt);
    reduceS<64><<<NN/4, 256, 0, stream>>>(h2bf, payload, offs, invc, Abuf);
    gemmS<52,1><<<NPAD/16, 256, 0, stream>>>(Abuf, Bp3, b3, batch, h2bf, pooled, gcnt);
    head_k   <<<1, 128, 0, stream>>>(pooled, gcnt, fcw, fcb, out);
}

// Round 4
// 536.431 us; speedup vs baseline: 1.5595x; 1.4197x over previous
//
#include <hip/hip_runtime.h>

#define NN 50000
#define NE 800000
#define NG 128

typedef unsigned int uint;
typedef unsigned short ushort;
typedef __attribute__((ext_vector_type(8))) short short8;
typedef __attribute__((ext_vector_type(4))) float f32x4;

__device__ __forceinline__ float bf2f(ushort u){ union{uint i; float f;} v; v.i=(uint)u<<16; return v.f; }
__device__ __forceinline__ ushort f2bf(float f){ union{float f; uint i;} v; v.f=f; return (ushort)((v.i + 0x7FFFu + ((v.i>>16)&1u))>>16); }

// ---------------- zero scratch re-initialized every call ----------------
__global__ void zero_k(int* hist, float* pooled, int* gcnt){
    int i = blockIdx.x*blockDim.x + threadIdx.x;
    if (i < NN) hist[i] = 0;
    if (i < NG*64) pooled[i] = 0.f;
    if (i < NG) gcnt[i] = 0;
}

// ---------------- per-edge data {src|lx|ly, fx, fy} + dst histogram ----------------
__global__ void coeff_k(const float* __restrict__ pseudo, const int* __restrict__ ei,
                        uint4* __restrict__ edata, int* __restrict__ hist){
    int e = blockIdx.x*blockDim.x + threadIdx.x;
    if (e >= NE) return;
    float2 ps = *(const float2*)(pseudo + 2*(size_t)e);
    float px = ps.x * 4.0f, py = ps.y * 4.0f;
    int lx = min(max((int)floorf(px), 0), 3);
    int ly = min(max((int)floorf(py), 0), 3);
    float fx = px - (float)lx, fy = py - (float)ly;
    uint meta = (uint)ei[e] | ((uint)lx<<16) | ((uint)ly<<18);   // src < 65536
    edata[e] = make_uint4(meta, __float_as_uint(fx), __float_as_uint(fy), 0u);
    atomicAdd(&hist[ei[NE + e]], 1);
}

// ---------------- exclusive scan of hist -> offs, cursor, inv_cnt ----------------
__global__ __launch_bounds__(1024) void scan_k(const int* __restrict__ hist, int* __restrict__ offs,
                                               int* __restrict__ cursor, float* __restrict__ invc){
    __shared__ int part[1024];
    int t = threadIdx.x;
    const int CH = (NN + 1023) / 1024;
    int base = t * CH;
    int lim = min(base + CH, NN);
    int s = 0;
    for (int i = base; i < lim; ++i) s += hist[i];
    part[t] = s; __syncthreads();
    for (int o = 1; o < 1024; o <<= 1){
        int v = (t >= o) ? part[t-o] : 0;
        __syncthreads();
        part[t] += v;
        __syncthreads();
    }
    int run = (t == 0) ? 0 : part[t-1];
    for (int i = base; i < lim; ++i){
        int h = hist[i];
        offs[i] = run; cursor[i] = run;
        invc[i] = 1.0f / (float)max(h, 1);
        run += h;
    }
    if (t == 1023) offs[NN] = part[1023];
}

// ---------------- counting sort: payload[pos] = edata[e] (16B) ----------------
__global__ void scatter_k(const int* __restrict__ ei, const uint4* __restrict__ edata,
                          int* __restrict__ cursor, uint4* __restrict__ payload){
    int e = blockIdx.x*blockDim.x + threadIdx.x;
    if (e >= NE) return;
    int dst = ei[NE + e];
    int pos = atomicAdd(&cursor[dst], 1);
    payload[pos] = edata[e];
}

// ---------------- pack [Wflat;root] into MFMA B-fragment layout, bf16 ----------------
// Bp[(kt*4+ct)*512 + lane*8 + j] = Bmat[kt*32 + (lane>>4)*8 + j][ct*16 + (lane&15)]
template<int IN>
__global__ void wprep_k(const float* __restrict__ W, const float* __restrict__ root, ushort* __restrict__ Bp){
    const int total = 26*IN*64;
    int tid = blockIdx.x*blockDim.x + threadIdx.x;
    if (tid >= total) return;
    int j    = tid & 7;
    int lane = (tid >> 3) & 63;
    int ctkt = tid >> 9;
    int ct   = ctkt & 3;
    int kt   = ctkt >> 2;
    int kk   = kt*32 + (lane>>4)*8 + j;
    int col  = ct*16 + (lane & 15);
    float v;
    if (kk < 25*IN){ int k = kk / IN; int i = kk % IN; v = W[((size_t)k*IN + i)*64 + col]; }
    else           { v = root[(size_t)(kk - 25*IN)*64 + col]; }
    Bp[tid] = f2bf(v);
}

// ---------------- layer 1: CSR reduce with tiny W1 in LDS (in=1, out=32) ----------------
__global__ __launch_bounds__(256) void reduce1_k(const float* __restrict__ x, const uint4* __restrict__ payload,
                                                 const int* __restrict__ offs, const float* __restrict__ invc,
                                                 const float* __restrict__ W1, const float* __restrict__ root1,
                                                 const float* __restrict__ b1, ushort* __restrict__ h1bf){
    __shared__ float w1s[25*32];
    for (int i = threadIdx.x; i < 25*32; i += 256) w1s[i] = W1[i];
    __syncthreads();
    int wid  = threadIdx.x >> 6;
    int lane = threadIdx.x & 63;
    int o    = lane & 31;
    int half = lane >> 5;
    int d    = blockIdx.x*4 + wid;
    int s = offs[d], e = offs[d+1];
    float acc = 0.f;
#define EDGE1(PL, XS) { uint meta = (PL).x; \
    int lx = (meta>>16)&3, ly = (meta>>18)&3; \
    float fx = __uint_as_float((PL).y), fy = __uint_as_float((PL).z); \
    float gx = 1.f - fx, gy = 1.f - fy; \
    int ka = ly*5 + lx + half; \
    float wa = half ? fx*gy : gx*gy; \
    float wb = half ? fx*fy : gx*fy; \
    acc += (wa*w1s[ka*32 + o] + wb*w1s[(ka+5)*32 + o]) * (XS); }
    int p = s;
    for (; p + 2 <= e; p += 2){
        uint4 A0 = payload[p], A1 = payload[p+1];
        float x0 = x[A0.x & 0xFFFF];
        float x1 = x[A1.x & 0xFFFF];
        EDGE1(A0, x0) EDGE1(A1, x1)
    }
    if (p < e){
        uint4 A0 = payload[p];
        float x0 = x[A0.x & 0xFFFF];
        EDGE1(A0, x0)
    }
#undef EDGE1
    acc += __shfl_xor(acc, 32);
    if (half == 0){
        float val = acc*invc[d] + x[d]*root1[o] + b1[o];
        val = val > 0.f ? val : expm1f(val);
        h1bf[(size_t)d*32 + o] = f2bf(val);
    }
}

// ---------------- fused layer: edge-accumulate S in LDS, convert, GEMM, epilogue ----------------
// IN=32: NND=16 nodes/block (2 per wave via half-waves), MODE0 -> write hout bf16
// IN=64: NND=8  nodes/block (1 per wave),                MODE1 -> pool into pooled/gcnt
template<int IN, int NND, int MODE>
__global__ __launch_bounds__(512) void fused_layer(
        const ushort* __restrict__ hin, const uint4* __restrict__ payload,
        const int* __restrict__ offs, const float* __restrict__ invc,
        const ushort* __restrict__ Bp, const float* __restrict__ bias,
        const int* __restrict__ batch, ushort* __restrict__ hout,
        float* __restrict__ pooled, int* __restrict__ gcnt)
{
    constexpr int KT  = 26*IN/32;       // 26 / 52
    constexpr int KH  = KT/2;           // 13 / 26
    constexpr int SP  = 25*IN + 4;      // f32 LDS row stride (pad breaks bank alias)
    constexpr int SBP = 26*IN + 8;      // bf16 LDS row stride (S + h-root columns)
    __shared__ __align__(16) float Sf[NND*SP];
    __shared__ float invS[NND];
    ushort* Sb   = (ushort*)Sf;                 // bf16 A-tile, overlays Sf after convert
    float*  red  = Sf + (NND*SBP)/2;            // [4][64][4] f32 partials (past Sb bytes)
    ushort* outB = (ushort*)(red + 1024);       // MODE0 staging [NND][64] bf16
    float*  outF = red + 1024;                  // MODE1 staging [NND][64] f32

    int tid = threadIdx.x, lane = tid & 63, w = tid >> 6;
    int d0 = blockIdx.x * NND;

    // 1. zero S
    for (int i = tid; i < NND*SP; i += 512) Sf[i] = 0.f;
    if (tid < NND) invS[tid] = invc[d0 + tid];
    __syncthreads();

    // 2. edge phase
    {
        int node, li;
        if (IN == 64){ node = w;                  li = lane;      }
        else         { node = 2*w + (lane >> 5);  li = lane & 31; }
        int dd = d0 + node;
        int s = offs[dd], e = offs[dd+1];
        float* Sw = Sf + node*SP;
#define UPD(PL, XS) { uint meta = (PL).x; \
        int lx = (meta>>16)&3, ly = (meta>>18)&3; \
        float fx = __uint_as_float((PL).y), fy = __uint_as_float((PL).z); \
        float gx = 1.f - fx, gy = 1.f - fy; \
        int b00 = (ly*5 + lx)*IN + li; \
        Sw[b00]      += gx*gy*(XS); \
        Sw[b00+IN]   += fx*gy*(XS); \
        Sw[b00+5*IN] += gx*fy*(XS); \
        Sw[b00+6*IN] += fx*fy*(XS); }
        int p = s;
        for (; p + 2 <= e; p += 2){
            uint4 p0 = payload[p], p1 = payload[p+1];
            float x0 = bf2f(hin[(size_t)(p0.x & 0xFFFF)*IN + li]);
            float x1 = bf2f(hin[(size_t)(p1.x & 0xFFFF)*IN + li]);
            UPD(p0, x0) UPD(p1, x1)
        }
        if (p < e){
            uint4 p0 = payload[p];
            float x0 = bf2f(hin[(size_t)(p0.x & 0xFFFF)*IN + li]);
            UPD(p0, x0)
        }
#undef UPD
    }
    __syncthreads();

    // 3. convert to bf16 A-tile (reg-staged: Sb overlays Sf)
    {
        float vals[26];
        int cnt = 0;
        for (int i = tid; i < NND*26*IN; i += 512, ++cnt){
            int n = i / (26*IN), c = i - n*(26*IN);
            vals[cnt] = (c < 25*IN) ? Sf[n*SP + c] * invS[n]
                                    : bf2f(hin[(size_t)(d0+n)*IN + (c - 25*IN)]);
        }
        __syncthreads();
        cnt = 0;
        for (int i = tid; i < NND*26*IN; i += 512, ++cnt){
            int n = i / (26*IN), c = i - n*(26*IN);
            Sb[n*SBP + c] = f2bf(vals[cnt]);
        }
    }
    __syncthreads();

    // 4. GEMM: 8 waves = 4 col-tiles x 2 K-halves
    int ct = w & 3, kh = w >> 2;
    int row  = lane & 15;
    int node = (NND == 16) ? row : (row & 7);
    int cg   = (lane >> 4) * 8;
    f32x4 acc = {0.f,0.f,0.f,0.f};
    {
        const ushort* abase = Sb + node*SBP + cg;
        const ushort* bb    = Bp + ct*512 + lane*8;
        int ktb = kh*KH;
        #pragma unroll
        for (int k = 0; k < KH; ++k){
            int kt = ktb + k;
            short8 a = *(const short8*)(abase + kt*32);
            short8 b = *(const short8*)(bb + (size_t)kt*2048);
            acc = __builtin_amdgcn_mfma_f32_16x16x32_bf16(a, b, acc, 0, 0, 0);
        }
    }
    // 5. deposit K-half partials
    if (kh == 1){
        float* r = red + (ct*64 + lane)*4;
        r[0]=acc[0]; r[1]=acc[1]; r[2]=acc[2]; r[3]=acc[3];
    }
    __syncthreads();
    // 6. finalize
    if (kh == 0){
        const float* r = red + (ct*64 + lane)*4;
        int rowg = lane >> 4;
        int colb = lane & 15, col = ct*16 + colb;
        float bs = bias[col];
        #pragma unroll
        for (int j = 0; j < 4; ++j){
            int rr = rowg*4 + j;
            float v = acc[j] + r[j] + bs;
            v = v > 0.f ? v : expm1f(v);
            if (MODE == 0) outB[rr*64 + col] = f2bf(v);
            else if (rr < NND) outF[rr*64 + col] = v;
        }
    }
    __syncthreads();
    // 7. output
    if (MODE == 0){
        // NND*64 bf16 = contiguous block of rows d0..d0+NND-1
        uint* dst = (uint*)(hout + (size_t)d0*64);
        const uint* srcp = (const uint*)outB;
        for (int i = tid; i < NND*32; i += 512) dst[i] = srcp[i];
    } else {
        if (w == 0){
            int c = lane;                    // 64 cols
            float run = 0.f; int gprev = batch[d0];
            for (int r = 0; r < NND; ++r){
                int g = batch[d0 + r];
                if (g != gprev){ atomicAdd(&pooled[gprev*64 + c], run); run = 0.f; gprev = g; }
                run += outF[r*64 + c];
            }
            atomicAdd(&pooled[gprev*64 + c], run);
        } else if (w == 1 && lane == 0){
            int cnt = 0; int gprev = batch[d0];
            for (int r = 0; r < NND; ++r){
                int g = batch[d0 + r];
                if (g != gprev){ atomicAdd(&gcnt[gprev], cnt); cnt = 0; gprev = g; }
                cnt++;
            }
            atomicAdd(&gcnt[gprev], cnt);
        }
    }
}

// ---------------- head: graph mean-pool -> fc -> log_softmax ----------------
__global__ __launch_bounds__(128) void head_k(const float* __restrict__ pooled, const int* __restrict__ gcnt,
                                              const float* __restrict__ fcw, const float* __restrict__ fcb,
                                              float* __restrict__ out){
    int g = threadIdx.x;
    if (g >= NG) return;
    float inv = 1.0f / fmaxf((float)gcnt[g], 1.0f);
    float logits[10];
    #pragma unroll
    for (int c = 0; c < 10; ++c) logits[c] = fcb[c];
    for (int o = 0; o < 64; ++o){
        float m = pooled[g*64 + o] * inv;
        #pragma unroll
        for (int c = 0; c < 10; ++c) logits[c] += m * fcw[o*10 + c];
    }
    float mx = logits[0];
    #pragma unroll
    for (int c = 1; c < 10; ++c) mx = fmaxf(mx, logits[c]);
    float ssum = 0.f;
    #pragma unroll
    for (int c = 0; c < 10; ++c) ssum += expf(logits[c] - mx);
    float lse = logf(ssum) + mx;
    #pragma unroll
    for (int c = 0; c < 10; ++c) out[g*10 + c] = logits[c] - lse;
}

extern "C" void kernel_launch(void* const* d_in, const int* in_sizes, int n_in,
                              void* d_out, int out_size, void* d_ws, size_t ws_size,
                              hipStream_t stream) {
    const float* x      = (const float*)d_in[0];
    const float* pseudo = (const float*)d_in[2];
    const int*   ei     = (const int*)  d_in[3];
    const int*   batch  = (const int*)  d_in[4];
    const float* W1     = (const float*)d_in[5];
    const float* root1  = (const float*)d_in[6];
    const float* b1     = (const float*)d_in[7];
    const float* W2     = (const float*)d_in[8];
    const float* root2  = (const float*)d_in[9];
    const float* b2     = (const float*)d_in[10];
    const float* W3     = (const float*)d_in[11];
    const float* root3  = (const float*)d_in[12];
    const float* b3     = (const float*)d_in[13];
    const float* fcw    = (const float*)d_in[14];
    const float* fcb    = (const float*)d_in[15];
    float* out = (float*)d_out;

    char* ws = (char*)d_ws;
    size_t off = 0;
    auto alloc = [&](size_t bytes)->char*{ char* p = ws + off; off += (bytes + 255) / 256 * 256; return p; };
    uint4*  edata  = (uint4*) alloc((size_t)NE*16);
    uint4*  payload= (uint4*) alloc((size_t)NE*16);
    ushort* h1bf   = (ushort*)alloc((size_t)NN*32*2);
    ushort* h2bf   = (ushort*)alloc((size_t)NN*64*2);
    int*    hist   = (int*)   alloc((size_t)NN*4);
    int*    offs   = (int*)   alloc((size_t)(NN+1)*4);
    int*    cursor = (int*)   alloc((size_t)NN*4);
    float*  invc   = (float*) alloc((size_t)NN*4);
    ushort* Bp2    = (ushort*)alloc((size_t)26*2048*2);
    ushort* Bp3    = (ushort*)alloc((size_t)52*2048*2);
    float*  pooled = (float*) alloc((size_t)NG*64*4);
    int*    gcnt   = (int*)   alloc((size_t)NG*4);
    (void)ws_size; (void)in_sizes; (void)n_in; (void)out_size;

    zero_k   <<<(NN+255)/256, 256, 0, stream>>>(hist, pooled, gcnt);
    coeff_k  <<<(NE+255)/256, 256, 0, stream>>>(pseudo, ei, edata, hist);
    scan_k   <<<1, 1024, 0, stream>>>(hist, offs, cursor, invc);
    scatter_k<<<(NE+255)/256, 256, 0, stream>>>(ei, edata, cursor, payload);
    wprep_k<32><<<(26*32*64 + 255)/256, 256, 0, stream>>>(W2, root2, Bp2);
    wprep_k<64><<<(26*64*64 + 255)/256, 256, 0, stream>>>(W3, root3, Bp3);
    reduce1_k<<<NN/4, 256, 0, stream>>>(x, payload, offs, invc, W1, root1, b1, h1bf);
    fused_layer<32,16,0><<<NN/16, 512, 0, stream>>>(h1bf, payload, offs, invc, Bp2, b2, batch, h2bf, pooled, gcnt);
    fused_layer<64, 8,1><<<NN/8,  512, 0, stream>>>(h2bf, payload, offs, invc, Bp3, b3, batch, h2bf, pooled, gcnt);
    head_k   <<<1, 128, 0, stream>>>(pooled, gcnt, fcw, fcb, out);
}

// Round 5
// 449.556 us; speedup vs baseline: 1.8609x; 1.1932x over previous
//
#include <hip/hip_runtime.h>

#define NN 50000
#define NE 800000
#define NG 128
#define NB_SCAN 196   // ceil(NN/256)

typedef unsigned int uint;
typedef unsigned short ushort;
typedef __attribute__((ext_vector_type(8))) short short8;
typedef __attribute__((ext_vector_type(4))) float f32x4;

__device__ __forceinline__ float bf2f(ushort u){ union{uint i; float f;} v; v.i=(uint)u<<16; return v.f; }
__device__ __forceinline__ ushort f2bf(float f){ union{float f; uint i;} v; v.f=f; return (ushort)((v.i + 0x7FFFu + ((v.i>>16)&1u))>>16); }

// ---------------- zero scratch re-initialized every call ----------------
__global__ void zero_k(int* hist, float* pooled, int* gcnt){
    int i = blockIdx.x*blockDim.x + threadIdx.x;
    if (i < NN) hist[i] = 0;
    if (i < NG*64) pooled[i] = 0.f;
    if (i < NG) gcnt[i] = 0;
}

// ---------------- dst histogram ----------------
__global__ void hist_k(const int* __restrict__ ei, int* __restrict__ hist){
    int e = blockIdx.x*blockDim.x + threadIdx.x;
    if (e < NE) atomicAdd(&hist[ei[NE + e]], 1);
}

// ---------------- hierarchical exclusive scan ----------------
__global__ __launch_bounds__(256) void scan1(const int* __restrict__ hist, int* __restrict__ bsum){
    __shared__ int sm[256];
    int t = threadIdx.x, i = blockIdx.x*256 + t;
    sm[t] = (i < NN) ? hist[i] : 0;
    __syncthreads();
    for (int o = 128; o > 0; o >>= 1){ if (t < o) sm[t] += sm[t+o]; __syncthreads(); }
    if (t == 0) bsum[blockIdx.x] = sm[0];
}
__global__ __launch_bounds__(256) void scan2(const int* __restrict__ bsum, int* __restrict__ bpre){
    __shared__ int sm[256];
    int t = threadIdx.x;
    int v = (t < NB_SCAN) ? bsum[t] : 0;
    sm[t] = v; __syncthreads();
    int acc = v;
    for (int o = 1; o < 256; o <<= 1){
        int u = (t >= o) ? sm[t-o] : 0; __syncthreads();
        acc += u; sm[t] = acc; __syncthreads();
    }
    if (t < NB_SCAN) bpre[t] = acc - v;
}
__global__ __launch_bounds__(256) void scan3(const int* __restrict__ hist, const int* __restrict__ bpre,
                                             int* __restrict__ offs, int* __restrict__ cursor,
                                             float* __restrict__ invc){
    __shared__ int sm[256];
    int t = threadIdx.x, b = blockIdx.x, i = b*256 + t;
    int v = (i < NN) ? hist[i] : 0;
    sm[t] = v; __syncthreads();
    int acc = v;
    for (int o = 1; o < 256; o <<= 1){
        int u = (t >= o) ? sm[t-o] : 0; __syncthreads();
        acc += u; sm[t] = acc; __syncthreads();
    }
    int excl = acc - v + bpre[b];
    if (i < NN){ offs[i] = excl; cursor[i] = excl; invc[i] = 1.0f/(float)max(v,1); }
    if (i == NN-1) offs[NN] = NE;
}

// ---------------- counting sort: recompute spline data, scatter payload (16B) ----------------
__global__ void scatter_k(const int* __restrict__ ei, const float* __restrict__ pseudo,
                          int* __restrict__ cursor, uint4* __restrict__ payload){
    int e = blockIdx.x*blockDim.x + threadIdx.x;
    if (e >= NE) return;
    float2 ps = *(const float2*)(pseudo + 2*(size_t)e);
    float px = ps.x * 4.0f, py = ps.y * 4.0f;
    int lx = min(max((int)floorf(px), 0), 3);
    int ly = min(max((int)floorf(py), 0), 3);
    float fx = px - (float)lx, fy = py - (float)ly;
    uint meta = (uint)ei[e] | ((uint)lx<<16) | ((uint)ly<<18);   // src < 65536
    int dst = ei[NE + e];
    int pos = atomicAdd(&cursor[dst], 1);
    payload[pos] = make_uint4(meta, __float_as_uint(fx), __float_as_uint(fy), 0u);
}

// ---------------- pack [Wflat;root] into MFMA B-fragment layout, bf16 ----------------
// Bp[(kt*4+ct)*512 + lane*8 + j] = Bmat[kt*32 + (lane>>4)*8 + j][ct*16 + (lane&15)]
template<int IN>
__global__ void wprep_k(const float* __restrict__ W, const float* __restrict__ root, ushort* __restrict__ Bp){
    const int total = 26*IN*64;
    int tid = blockIdx.x*blockDim.x + threadIdx.x;
    if (tid >= total) return;
    int j    = tid & 7;
    int lane = (tid >> 3) & 63;
    int ctkt = tid >> 9;
    int ct   = ctkt & 3;
    int kt   = ctkt >> 2;
    int kk   = kt*32 + (lane>>4)*8 + j;
    int col  = ct*16 + (lane & 15);
    float v;
    if (kk < 25*IN){ int k = kk / IN; int i = kk % IN; v = W[((size_t)k*IN + i)*64 + col]; }
    else           { v = root[(size_t)(kk - 25*IN)*64 + col]; }
    Bp[tid] = f2bf(v);
}

// ---------------- layer 1: CSR reduce with tiny W1 in LDS (in=1, out=32) ----------------
__global__ __launch_bounds__(256) void reduce1_k(const float* __restrict__ x, const uint4* __restrict__ payload,
                                                 const int* __restrict__ offs, const float* __restrict__ invc,
                                                 const float* __restrict__ W1, const float* __restrict__ root1,
                                                 const float* __restrict__ b1, ushort* __restrict__ h1bf){
    __shared__ float w1s[25*32];
    for (int i = threadIdx.x; i < 25*32; i += 256) w1s[i] = W1[i];
    __syncthreads();
    int wid  = threadIdx.x >> 6;
    int lane = threadIdx.x & 63;
    int o    = lane & 31;
    int half = lane >> 5;
    int d    = blockIdx.x*4 + wid;
    int s = offs[d], e = offs[d+1];
    float acc = 0.f;
#define EDGE1(PL, XS) { uint meta = (PL).x; \
    int lx = (meta>>16)&3, ly = (meta>>18)&3; \
    float fx = __uint_as_float((PL).y), fy = __uint_as_float((PL).z); \
    float gx = 1.f - fx, gy = 1.f - fy; \
    int ka = ly*5 + lx + half; \
    float wa = half ? fx*gy : gx*gy; \
    float wb = half ? fx*fy : gx*fy; \
    acc += (wa*w1s[ka*32 + o] + wb*w1s[(ka+5)*32 + o]) * (XS); }
    int p = s;
    for (; p + 2 <= e; p += 2){
        uint4 A0 = payload[p], A1 = payload[p+1];
        float x0 = x[A0.x & 0xFFFF];
        float x1 = x[A1.x & 0xFFFF];
        EDGE1(A0, x0) EDGE1(A1, x1)
    }
    if (p < e){
        uint4 A0 = payload[p];
        float x0 = x[A0.x & 0xFFFF];
        EDGE1(A0, x0)
    }
#undef EDGE1
    acc += __shfl_xor(acc, 32);
    if (half == 0){
        float val = acc*invc[d] + x[d]*root1[o] + b1[o];
        val = val > 0.f ? val : expm1f(val);
        h1bf[(size_t)d*32 + o] = f2bf(val);
    }
}

// ---------------- fused layer: float2 edge-accumulate, vector convert, GEMM, epilogue ----------------
// 256 threads (4 waves). IN=32: 4 nodes/wave (NND=16), MODE0 -> hout. IN=64: 2 nodes/wave (NND=8), MODE1 -> pool.
template<int IN, int NND, int MODE>
__global__ __launch_bounds__(256, 3) void fused_layer(
        const ushort* __restrict__ hin, const uint4* __restrict__ payload,
        const int* __restrict__ offs, const float* __restrict__ invc,
        const ushort* __restrict__ Bp, const float* __restrict__ bias,
        const int* __restrict__ batch, ushort* __restrict__ hout,
        float* __restrict__ pooled, int* __restrict__ gcnt)
{
    constexpr int KT  = 26*IN/32;               // 26 / 52
    constexpr int SP  = 25*IN + 4;              // f32 per-node stride (even -> float2 aligned)
    constexpr int SBP = (IN == 64) ? 1688 : 856; // ushort stride: *2 % 16 == 0 (b128 ok), /2 % 32 == 12 (bank spread)
    constexpr int NPW = NND/4;                  // nodes per wave
    constexpr int LPN = 64/NPW;                 // lanes per node (32 / 16), 2 features per lane
    constexpr int STG = 6912;                   // f32 offset of output staging inside Sf (> Sb extent)
    __shared__ __align__(16) float Sf[NND*SP];
    __shared__ float invS[NND];
    ushort* Sb   = (ushort*)Sf;                 // bf16 A-tile overlays Sf after convert
    float*  outF = Sf + STG;
    ushort* outB = (ushort*)(Sf + STG);

    int tid = threadIdx.x, lane = tid & 63, w = tid >> 6;
    int d0 = blockIdx.x * NND;

    // 1. zero S
    for (int i = tid; i < NND*SP; i += 256) Sf[i] = 0.f;
    if (tid < NND) invS[tid] = invc[d0 + tid];
    __syncthreads();

    // 2. edge phase: each lane owns a feature PAIR; NPW nodes share the wave's instruction stream
    {
        int sub  = lane / LPN;
        int li   = lane % LPN;
        int node = w*NPW + sub;
        int dd   = d0 + node;
        int s = offs[dd], e = offs[dd+1];
        float* Sw = Sf + node*SP;
        int f0 = 2*li;
        for (int p = s; p < e; ++p){
            uint4 pl = payload[p];
            uint meta = pl.x;
            int src = meta & 0xFFFF;
            int lx = (meta>>16)&3, ly = (meta>>18)&3;
            float fx = __uint_as_float(pl.y), fy = __uint_as_float(pl.z);
            float gx = 1.f - fx, gy = 1.f - fy;
            uint hx = *(const uint*)(hin + (size_t)src*IN + f0);
            float x0 = bf2f((ushort)hx), x1 = bf2f((ushort)(hx>>16));
            int b00 = (ly*5 + lx)*IN + f0;
            float2* q0 = (float2*)(Sw + b00);
            float2* q1 = (float2*)(Sw + b00 + IN);
            float2* q2 = (float2*)(Sw + b00 + 5*IN);
            float2* q3 = (float2*)(Sw + b00 + 6*IN);
            float w00 = gx*gy, w10 = fx*gy, w01 = gx*fy, w11 = fx*fy;
            float2 v0 = *q0, v1 = *q1, v2 = *q2, v3 = *q3;
            v0.x += w00*x0; v0.y += w00*x1;
            v1.x += w10*x0; v1.y += w10*x1;
            v2.x += w01*x0; v2.y += w01*x1;
            v3.x += w11*x0; v3.y += w11*x1;
            *q0 = v0; *q1 = v1; *q2 = v2; *q3 = v3;
        }
    }
    __syncthreads();

    // 3. convert to bf16 A-tile, float2-vectorized, fully static staging (26 iters exactly)
    {
        float2 vals[26];
        #pragma unroll
        for (int k = 0; k < 26; ++k){
            int i2 = tid + k*256;                 // < NND*13*IN == 6656
            int n = i2 / (13*IN), c = (i2 - n*(13*IN))*2;
            if (c < 25*IN){
                float2 sv = *(float2*)(Sf + n*SP + c);
                float ic = invS[n];
                vals[k] = make_float2(sv.x*ic, sv.y*ic);
            } else {
                uint hv = *(const uint*)(hin + (size_t)(d0+n)*IN + (c - 25*IN));
                vals[k] = make_float2(bf2f((ushort)hv), bf2f((ushort)(hv>>16)));
            }
        }
        __syncthreads();
        #pragma unroll
        for (int k = 0; k < 26; ++k){
            int i2 = tid + k*256;
            int n = i2 / (13*IN), c = (i2 - n*(13*IN))*2;
            uint pk = ((uint)f2bf(vals[k].y) << 16) | (uint)f2bf(vals[k].x);
            *(uint*)(Sb + n*SBP + c) = pk;
        }
    }
    __syncthreads();

    // 4. GEMM: wave w = column-tile ct, full K per wave
    {
        int ct = w, row = lane & 15;
        int node = (NND == 16) ? row : (row & 7);
        int cg = (lane >> 4)*8;
        f32x4 acc = {0.f,0.f,0.f,0.f};
        const ushort* ab = Sb + node*SBP + cg;
        const ushort* bb = Bp + ct*512 + (size_t)lane*8;
        #pragma unroll
        for (int kt = 0; kt < KT; ++kt){
            short8 a = *(const short8*)(ab + kt*32);
            short8 b = *(const short8*)(bb + (size_t)kt*2048);
            acc = __builtin_amdgcn_mfma_f32_16x16x32_bf16(a, b, acc, 0, 0, 0);
        }
        int col = ct*16 + (lane & 15);
        float bs = bias[col];
        int r0 = (lane >> 4)*4;
        #pragma unroll
        for (int j = 0; j < 4; ++j){
            int rr = r0 + j;
            float v = acc[j] + bs;
            v = v > 0.f ? v : expm1f(v);
            if (NND == 16 || rr < 8){
                if (MODE == 0) outB[rr*64 + col] = f2bf(v);
                else           outF[rr*64 + col] = v;
            }
        }
    }
    __syncthreads();

    // 5. output
    if (MODE == 0){
        uint* dst = (uint*)(hout + (size_t)d0*64);
        const uint* srcp = (const uint*)outB;
        for (int i = tid; i < NND*32; i += 256) dst[i] = srcp[i];
    } else {
        if (w == 0){
            int c = lane;
            float run = 0.f; int gprev = batch[d0];
            for (int r = 0; r < NND; ++r){
                int g = batch[d0 + r];
                if (g != gprev){ atomicAdd(&pooled[gprev*64 + c], run); run = 0.f; gprev = g; }
                run += outF[r*64 + c];
            }
            atomicAdd(&pooled[gprev*64 + c], run);
        } else if (w == 1 && lane == 0){
            int cnt = 0; int gprev = batch[d0];
            for (int r = 0; r < NND; ++r){
                int g = batch[d0 + r];
                if (g != gprev){ atomicAdd(&gcnt[gprev], cnt); cnt = 0; gprev = g; }
                cnt++;
            }
            atomicAdd(&gcnt[gprev], cnt);
        }
    }
}

// ---------------- head: graph mean-pool -> fc -> log_softmax ----------------
__global__ __launch_bounds__(128) void head_k(const float* __restrict__ pooled, const int* __restrict__ gcnt,
                                              const float* __restrict__ fcw, const float* __restrict__ fcb,
                                              float* __restrict__ out){
    int g = threadIdx.x;
    if (g >= NG) return;
    float inv = 1.0f / fmaxf((float)gcnt[g], 1.0f);
    float logits[10];
    #pragma unroll
    for (int c = 0; c < 10; ++c) logits[c] = fcb[c];
    for (int o = 0; o < 64; ++o){
        float m = pooled[g*64 + o] * inv;
        #pragma unroll
        for (int c = 0; c < 10; ++c) logits[c] += m * fcw[o*10 + c];
    }
    float mx = logits[0];
    #pragma unroll
    for (int c = 1; c < 10; ++c) mx = fmaxf(mx, logits[c]);
    float ssum = 0.f;
    #pragma unroll
    for (int c = 0; c < 10; ++c) ssum += expf(logits[c] - mx);
    float lse = logf(ssum) + mx;
    #pragma unroll
    for (int c = 0; c < 10; ++c) out[g*10 + c] = logits[c] - lse;
}

extern "C" void kernel_launch(void* const* d_in, const int* in_sizes, int n_in,
                              void* d_out, int out_size, void* d_ws, size_t ws_size,
                              hipStream_t stream) {
    const float* x      = (const float*)d_in[0];
    const float* pseudo = (const float*)d_in[2];
    const int*   ei     = (const int*)  d_in[3];
    const int*   batch  = (const int*)  d_in[4];
    const float* W1     = (const float*)d_in[5];
    const float* root1  = (const float*)d_in[6];
    const float* b1     = (const float*)d_in[7];
    const float* W2     = (const float*)d_in[8];
    const float* root2  = (const float*)d_in[9];
    const float* b2     = (const float*)d_in[10];
    const float* W3     = (const float*)d_in[11];
    const float* root3  = (const float*)d_in[12];
    const float* b3     = (const float*)d_in[13];
    const float* fcw    = (const float*)d_in[14];
    const float* fcb    = (const float*)d_in[15];
    float* out = (float*)d_out;

    char* ws = (char*)d_ws;
    size_t off = 0;
    auto alloc = [&](size_t bytes)->char*{ char* p = ws + off; off += (bytes + 255) / 256 * 256; return p; };
    uint4*  payload= (uint4*) alloc((size_t)NE*16);
    ushort* h1bf   = (ushort*)alloc((size_t)NN*32*2);
    ushort* h2bf   = (ushort*)alloc((size_t)NN*64*2);
    int*    hist   = (int*)   alloc((size_t)NN*4);
    int*    offs   = (int*)   alloc((size_t)(NN+1)*4);
    int*    cursor = (int*)   alloc((size_t)NN*4);
    float*  invc   = (float*) alloc((size_t)NN*4);
    int*    bsum   = (int*)   alloc((size_t)NB_SCAN*4);
    int*    bpre   = (int*)   alloc((size_t)NB_SCAN*4);
    ushort* Bp2    = (ushort*)alloc((size_t)26*2048*2);
    ushort* Bp3    = (ushort*)alloc((size_t)52*2048*2);
    float*  pooled = (float*) alloc((size_t)NG*64*4);
    int*    gcnt   = (int*)   alloc((size_t)NG*4);
    (void)ws_size; (void)in_sizes; (void)n_in; (void)out_size;

    zero_k   <<<(NN+255)/256, 256, 0, stream>>>(hist, pooled, gcnt);
    hist_k   <<<(NE+255)/256, 256, 0, stream>>>(ei, hist);
    scan1    <<<NB_SCAN, 256, 0, stream>>>(hist, bsum);
    scan2    <<<1, 256, 0, stream>>>(bsum, bpre);
    scan3    <<<NB_SCAN, 256, 0, stream>>>(hist, bpre, offs, cursor, invc);
    scatter_k<<<(NE+255)/256, 256, 0, stream>>>(ei, pseudo, cursor, payload);
    wprep_k<32><<<(26*32*64 + 255)/256, 256, 0, stream>>>(W2, root2, Bp2);
    wprep_k<64><<<(26*64*64 + 255)/256, 256, 0, stream>>>(W3, root3, Bp3);
    reduce1_k<<<NN/4, 256, 0, stream>>>(x, payload, offs, invc, W1, root1, b1, h1bf);
    fused_layer<32,16,0><<<NN/16, 256, 0, stream>>>(h1bf, payload, offs, invc, Bp2, b2, batch, h2bf, pooled, gcnt);
    fused_layer<64, 8,1><<<NN/8,  256, 0, stream>>>(h2bf, payload, offs, invc, Bp3, b3, batch, h2bf, pooled, gcnt);
    head_k   <<<1, 128, 0, stream>>>(pooled, gcnt, fcw, fcb, out);
}

// Round 6
// 441.402 us; speedup vs baseline: 1.8953x; 1.0185x over previous
//
#include <hip/hip_runtime.h>

#define NN 50000
#define NE 800000
#define NG 128
#define NB_SCAN 196   // ceil(NN/256)

typedef unsigned int uint;
typedef unsigned short ushort;
typedef __attribute__((ext_vector_type(8))) short short8;
typedef __attribute__((ext_vector_type(4))) float f32x4;

__device__ __forceinline__ float bf2f(ushort u){ union{uint i; float f;} v; v.i=(uint)u<<16; return v.f; }
__device__ __forceinline__ ushort f2bf(float f){ union{float f; uint i;} v; v.f=f; return (ushort)((v.i + 0x7FFFu + ((v.i>>16)&1u))>>16); }

// ---------------- zero scratch re-initialized every call ----------------
__global__ void zero_k(int* hist, float* pooled, int* gcnt){
    int i = blockIdx.x*blockDim.x + threadIdx.x;
    if (i < NN) hist[i] = 0;
    if (i < NG*64) pooled[i] = 0.f;
    if (i < NG) gcnt[i] = 0;
}

// ---------------- dst histogram ----------------
__global__ void hist_k(const int* __restrict__ ei, int* __restrict__ hist){
    int e = blockIdx.x*blockDim.x + threadIdx.x;
    if (e < NE) atomicAdd(&hist[ei[NE + e]], 1);
}

// ---------------- hierarchical exclusive scan ----------------
__global__ __launch_bounds__(256) void scan1(const int* __restrict__ hist, int* __restrict__ bsum){
    __shared__ int sm[256];
    int t = threadIdx.x, i = blockIdx.x*256 + t;
    sm[t] = (i < NN) ? hist[i] : 0;
    __syncthreads();
    for (int o = 128; o > 0; o >>= 1){ if (t < o) sm[t] += sm[t+o]; __syncthreads(); }
    if (t == 0) bsum[blockIdx.x] = sm[0];
}
__global__ __launch_bounds__(256) void scan2(const int* __restrict__ bsum, int* __restrict__ bpre){
    __shared__ int sm[256];
    int t = threadIdx.x;
    int v = (t < NB_SCAN) ? bsum[t] : 0;
    sm[t] = v; __syncthreads();
    int acc = v;
    for (int o = 1; o < 256; o <<= 1){
        int u = (t >= o) ? sm[t-o] : 0; __syncthreads();
        acc += u; sm[t] = acc; __syncthreads();
    }
    if (t < NB_SCAN) bpre[t] = acc - v;
}
__global__ __launch_bounds__(256) void scan3(const int* __restrict__ hist, const int* __restrict__ bpre,
                                             int* __restrict__ offs, int* __restrict__ cursor,
                                             float* __restrict__ invc){
    __shared__ int sm[256];
    int t = threadIdx.x, b = blockIdx.x, i = b*256 + t;
    int v = (i < NN) ? hist[i] : 0;
    sm[t] = v; __syncthreads();
    int acc = v;
    for (int o = 1; o < 256; o <<= 1){
        int u = (t >= o) ? sm[t-o] : 0; __syncthreads();
        acc += u; sm[t] = acc; __syncthreads();
    }
    int excl = acc - v + bpre[b];
    if (i < NN){ offs[i] = excl; cursor[i] = excl; invc[i] = 1.0f/(float)max(v,1); }
    if (i == NN-1) offs[NN] = NE;
}

// ---------------- counting sort: recompute spline data, scatter payload (16B) ----------------
__global__ void scatter_k(const int* __restrict__ ei, const float* __restrict__ pseudo,
                          int* __restrict__ cursor, uint4* __restrict__ payload){
    int e = blockIdx.x*blockDim.x + threadIdx.x;
    if (e >= NE) return;
    float2 ps = *(const float2*)(pseudo + 2*(size_t)e);
    float px = ps.x * 4.0f, py = ps.y * 4.0f;
    int lx = min(max((int)floorf(px), 0), 3);
    int ly = min(max((int)floorf(py), 0), 3);
    float fx = px - (float)lx, fy = py - (float)ly;
    uint meta = (uint)ei[e] | ((uint)lx<<16) | ((uint)ly<<18);   // src < 65536
    int dst = ei[NE + e];
    int pos = atomicAdd(&cursor[dst], 1);
    payload[pos] = make_uint4(meta, __float_as_uint(fx), __float_as_uint(fy), 0u);
}

// ---------------- pack [Wflat;root] into MFMA B-fragment layout, bf16 ----------------
// Bp[(kt*4+ct)*512 + lane*8 + j] = Bmat[kt*32 + (lane>>4)*8 + j][ct*16 + (lane&15)]
template<int IN>
__global__ void wprep_k(const float* __restrict__ W, const float* __restrict__ root, ushort* __restrict__ Bp){
    const int total = 26*IN*64;
    int tid = blockIdx.x*blockDim.x + threadIdx.x;
    if (tid >= total) return;
    int j    = tid & 7;
    int lane = (tid >> 3) & 63;
    int ctkt = tid >> 9;
    int ct   = ctkt & 3;
    int kt   = ctkt >> 2;
    int kk   = kt*32 + (lane>>4)*8 + j;
    int col  = ct*16 + (lane & 15);
    float v;
    if (kk < 25*IN){ int k = kk / IN; int i = kk % IN; v = W[((size_t)k*IN + i)*64 + col]; }
    else           { v = root[(size_t)(kk - 25*IN)*64 + col]; }
    Bp[tid] = f2bf(v);
}

// ---------------- layer 1: CSR reduce with tiny W1 in LDS (in=1, out=32) ----------------
__global__ __launch_bounds__(256) void reduce1_k(const float* __restrict__ x, const uint4* __restrict__ payload,
                                                 const int* __restrict__ offs, const float* __restrict__ invc,
                                                 const float* __restrict__ W1, const float* __restrict__ root1,
                                                 const float* __restrict__ b1, ushort* __restrict__ h1bf){
    __shared__ float w1s[25*32];
    for (int i = threadIdx.x; i < 25*32; i += 256) w1s[i] = W1[i];
    __syncthreads();
    int wid  = threadIdx.x >> 6;
    int lane = threadIdx.x & 63;
    int o    = lane & 31;
    int half = lane >> 5;
    int d    = blockIdx.x*4 + wid;
    int s = offs[d], e = offs[d+1];
    float acc = 0.f;
#define EDGE1(PL, XS) { uint meta = (PL).x; \
    int lx = (meta>>16)&3, ly = (meta>>18)&3; \
    float fx = __uint_as_float((PL).y), fy = __uint_as_float((PL).z); \
    float gx = 1.f - fx, gy = 1.f - fy; \
    int ka = ly*5 + lx + half; \
    float wa = half ? fx*gy : gx*gy; \
    float wb = half ? fx*fy : gx*fy; \
    acc += (wa*w1s[ka*32 + o] + wb*w1s[(ka+5)*32 + o]) * (XS); }
    int p = s;
    for (; p + 2 <= e; p += 2){
        uint4 A0 = payload[p], A1 = payload[p+1];
        float x0 = x[A0.x & 0xFFFF];
        float x1 = x[A1.x & 0xFFFF];
        EDGE1(A0, x0) EDGE1(A1, x1)
    }
    if (p < e){
        uint4 A0 = payload[p];
        float x0 = x[A0.x & 0xFFFF];
        EDGE1(A0, x0)
    }
#undef EDGE1
    acc += __shfl_xor(acc, 32);
    if (half == 0){
        float val = acc*invc[d] + x[d]*root1[o] + b1[o];
        val = val > 0.f ? val : expm1f(val);
        h1bf[(size_t)d*32 + o] = f2bf(val);
    }
}

// ---------------- fused layer, register-accumulated ----------------
// 512 threads = 8 waves = 8 nodes/block. Edge phase: S lives in 25 VGPRs per lane
// (lane owns one feature of one node); all 25 slots updated per edge via select-weights
// (static indexing, no LDS, no loop-carried RMW). Then bf16 A-tile -> LDS -> MFMA GEMM.
// IN=64: 1 edge/iter (wave-uniform payload). IN=32: half-waves do 2 edges/iter + shfl reduce.
template<int IN, int MODE>
__global__ __launch_bounds__(512) void fused_reg(
        const ushort* __restrict__ hin, const uint4* __restrict__ payload,
        const int* __restrict__ offs, const float* __restrict__ invc,
        const ushort* __restrict__ Bp, const float* __restrict__ bias,
        const int* __restrict__ batch, ushort* __restrict__ hout,
        float* __restrict__ pooled, int* __restrict__ gcnt)
{
    constexpr int KT = 26*IN/32;        // 26 / 52
    constexpr int KH = KT/2;
    constexpr int SW = 26*IN + 8;       // ushort stride: *2%16==0 (b128-aligned), /8 odd-ish (bank spread)
    __shared__ __align__(16) ushort Sb[8*SW];
    __shared__ float red[1024];         // [4][64][4] K-half partials
    __shared__ float outS[512];         // epilogue staging (f32 or bf16 view)

    int tid = threadIdx.x, lane = tid & 63, w = tid >> 6;
    int d0 = blockIdx.x * 8;
    int node = w, dd = d0 + node;

    // ---- edge phase (registers only) ----
    float acc[25];
    #pragma unroll
    for (int k = 0; k < 25; ++k) acc[k] = 0.f;

    int s = offs[dd], e = offs[dd+1];

#define EDGE_BODY(PLC, XS) { \
    uint meta = (PLC).x; \
    int lx = (meta>>16)&3, ly = (meta>>18)&3; \
    float fx = __uint_as_float((PLC).y), fy = __uint_as_float((PLC).z); \
    float gx = 1.f - fx, gy = 1.f - fy; \
    float tx[5], wy[5]; \
    _Pragma("unroll") \
    for (int i = 0; i < 5; ++i){ \
        float wxi = (i==lx) ? gx : ((i==lx+1) ? fx : 0.f); \
        tx[i] = wxi * (XS); \
        wy[i] = (i==ly) ? gy : ((i==ly+1) ? fy : 0.f); \
    } \
    _Pragma("unroll") \
    for (int j = 0; j < 5; ++j) \
        _Pragma("unroll") \
        for (int i = 0; i < 5; ++i) \
            acc[j*5+i] = fmaf(wy[j], tx[i], acc[j*5+i]); }

    if (IN == 64){
        uint4 plc = (s < e) ? payload[s] : make_uint4(0u,0u,0u,0u);
        for (int p = s; p < e; ++p){
            uint4 pln = (p+1 < e) ? payload[p+1] : plc;
            float xs = bf2f(hin[(size_t)(plc.x & 0xFFFF)*64 + lane]);
            EDGE_BODY(plc, xs)
            plc = pln;
        }
    } else {
        int half = lane >> 5, li = lane & 31;
        int p0 = s + half;
        uint4 plc = (p0 < e) ? payload[p0] : make_uint4(0u,0u,0u,0u);
        for (int p = p0; p < e; p += 2){
            uint4 pln = (p+2 < e) ? payload[p+2] : plc;
            float xs = bf2f(hin[(size_t)(plc.x & 0xFFFF)*32 + li]);
            EDGE_BODY(plc, xs)
            plc = pln;
        }
        #pragma unroll
        for (int k = 0; k < 25; ++k) acc[k] += __shfl_xor(acc[k], 32);
    }
#undef EDGE_BODY

    // ---- write bf16 A-tile row ----
    {
        float ic = invc[dd];
        if (IN == 64){
            #pragma unroll
            for (int k = 0; k < 25; ++k) Sb[node*SW + k*64 + lane] = f2bf(acc[k]*ic);
            Sb[node*SW + 25*64 + lane] = hin[(size_t)dd*64 + lane];
        } else {
            int half = lane >> 5, li = lane & 31;
            if (half == 0){
                #pragma unroll
                for (int k = 0; k < 25; ++k) Sb[node*SW + k*32 + li] = f2bf(acc[k]*ic);
                Sb[node*SW + 25*32 + li] = hin[(size_t)dd*32 + li];
            }
        }
    }
    __syncthreads();

    // ---- GEMM: 8 waves = 4 col-tiles x 2 K-halves; M=8 ----
    int ct = w & 3, kh = w >> 2;
    int row = lane & 15, node8 = row & 7, cg = (lane >> 4)*8;
    f32x4 acc4 = {0.f,0.f,0.f,0.f};
    {
        const ushort* ab = Sb + node8*SW + cg;
        const ushort* bb = Bp + ct*512 + (size_t)lane*8;
        #pragma unroll
        for (int k = 0; k < KH; ++k){
            int kt = kh*KH + k;
            short8 a = *(const short8*)(ab + kt*32);
            short8 b = *(const short8*)(bb + (size_t)kt*2048);
            acc4 = __builtin_amdgcn_mfma_f32_16x16x32_bf16(a, b, acc4, 0, 0, 0);
        }
    }
    if (kh == 1){
        float* r = red + (ct*64 + lane)*4;
        r[0]=acc4[0]; r[1]=acc4[1]; r[2]=acc4[2]; r[3]=acc4[3];
    }
    __syncthreads();
    if (kh == 0){
        const float* r = red + (ct*64 + lane)*4;
        int col = ct*16 + (lane & 15);
        float bs = bias[col];
        #pragma unroll
        for (int j = 0; j < 4; ++j){
            int rr = (lane >> 4)*4 + j;
            if (rr < 8){
                float v = acc4[j] + r[j] + bs;
                v = v > 0.f ? v : expm1f(v);
                if (MODE == 0) ((ushort*)outS)[rr*64 + col] = f2bf(v);
                else           outS[rr*64 + col] = v;
            }
        }
    }
    __syncthreads();

    // ---- output ----
    if (MODE == 0){
        uint* dst = (uint*)(hout + (size_t)d0*64);
        const uint* srcp = (const uint*)outS;
        for (int i = tid; i < 256; i += 512) dst[i] = srcp[i];
    } else {
        if (w == 0){
            int c = lane;
            float run = 0.f; int gprev = batch[d0];
            for (int r = 0; r < 8; ++r){
                int g = batch[d0 + r];
                if (g != gprev){ atomicAdd(&pooled[gprev*64 + c], run); run = 0.f; gprev = g; }
                run += outS[r*64 + c];
            }
            atomicAdd(&pooled[gprev*64 + c], run);
        } else if (w == 1 && lane == 0){
            int cnt = 0; int gprev = batch[d0];
            for (int r = 0; r < 8; ++r){
                int g = batch[d0 + r];
                if (g != gprev){ atomicAdd(&gcnt[gprev], cnt); cnt = 0; gprev = g; }
                cnt++;
            }
            atomicAdd(&gcnt[gprev], cnt);
        }
    }
}

// ---------------- head: graph mean-pool -> fc -> log_softmax ----------------
__global__ __launch_bounds__(128) void head_k(const float* __restrict__ pooled, const int* __restrict__ gcnt,
                                              const float* __restrict__ fcw, const float* __restrict__ fcb,
                                              float* __restrict__ out){
    int g = threadIdx.x;
    if (g >= NG) return;
    float inv = 1.0f / fmaxf((float)gcnt[g], 1.0f);
    float logits[10];
    #pragma unroll
    for (int c = 0; c < 10; ++c) logits[c] = fcb[c];
    for (int o = 0; o < 64; ++o){
        float m = pooled[g*64 + o] * inv;
        #pragma unroll
        for (int c = 0; c < 10; ++c) logits[c] += m * fcw[o*10 + c];
    }
    float mx = logits[0];
    #pragma unroll
    for (int c = 1; c < 10; ++c) mx = fmaxf(mx, logits[c]);
    float ssum = 0.f;
    #pragma unroll
    for (int c = 0; c < 10; ++c) ssum += expf(logits[c] - mx);
    float lse = logf(ssum) + mx;
    #pragma unroll
    for (int c = 0; c < 10; ++c) out[g*10 + c] = logits[c] - lse;
}

extern "C" void kernel_launch(void* const* d_in, const int* in_sizes, int n_in,
                              void* d_out, int out_size, void* d_ws, size_t ws_size,
                              hipStream_t stream) {
    const float* x      = (const float*)d_in[0];
    const float* pseudo = (const float*)d_in[2];
    const int*   ei     = (const int*)  d_in[3];
    const int*   batch  = (const int*)  d_in[4];
    const float* W1     = (const float*)d_in[5];
    const float* root1  = (const float*)d_in[6];
    const float* b1     = (const float*)d_in[7];
    const float* W2     = (const float*)d_in[8];
    const float* root2  = (const float*)d_in[9];
    const float* b2     = (const float*)d_in[10];
    const float* W3     = (const float*)d_in[11];
    const float* root3  = (const float*)d_in[12];
    const float* b3     = (const float*)d_in[13];
    const float* fcw    = (const float*)d_in[14];
    const float* fcb    = (const float*)d_in[15];
    float* out = (float*)d_out;

    char* ws = (char*)d_ws;
    size_t off = 0;
    auto alloc = [&](size_t bytes)->char*{ char* p = ws + off; off += (bytes + 255) / 256 * 256; return p; };
    uint4*  payload= (uint4*) alloc((size_t)NE*16);
    ushort* h1bf   = (ushort*)alloc((size_t)NN*32*2);
    ushort* h2bf   = (ushort*)alloc((size_t)NN*64*2);
    int*    hist   = (int*)   alloc((size_t)NN*4);
    int*    offs   = (int*)   alloc((size_t)(NN+1)*4);
    int*    cursor = (int*)   alloc((size_t)NN*4);
    float*  invc   = (float*) alloc((size_t)NN*4);
    int*    bsum   = (int*)   alloc((size_t)NB_SCAN*4);
    int*    bpre   = (int*)   alloc((size_t)NB_SCAN*4);
    ushort* Bp2    = (ushort*)alloc((size_t)26*2048*2);
    ushort* Bp3    = (ushort*)alloc((size_t)52*2048*2);
    float*  pooled = (float*) alloc((size_t)NG*64*4);
    int*    gcnt   = (int*)   alloc((size_t)NG*4);
    (void)ws_size; (void)in_sizes; (void)n_in; (void)out_size;

    zero_k   <<<(NN+255)/256, 256, 0, stream>>>(hist, pooled, gcnt);
    hist_k   <<<(NE+255)/256, 256, 0, stream>>>(ei, hist);
    scan1    <<<NB_SCAN, 256, 0, stream>>>(hist, bsum);
    scan2    <<<1, 256, 0, stream>>>(bsum, bpre);
    scan3    <<<NB_SCAN, 256, 0, stream>>>(hist, bpre, offs, cursor, invc);
    scatter_k<<<(NE+255)/256, 256, 0, stream>>>(ei, pseudo, cursor, payload);
    wprep_k<32><<<(26*32*64 + 255)/256, 256, 0, stream>>>(W2, root2, Bp2);
    wprep_k<64><<<(26*64*64 + 255)/256, 256, 0, stream>>>(W3, root3, Bp3);
    reduce1_k<<<NN/4, 256, 0, stream>>>(x, payload, offs, invc, W1, root1, b1, h1bf);
    fused_reg<32,0><<<NN/8, 512, 0, stream>>>(h1bf, payload, offs, invc, Bp2, b2, batch, h2bf, pooled, gcnt);
    fused_reg<64,1><<<NN/8, 512, 0, stream>>>(h2bf, payload, offs, invc, Bp3, b3, batch, h2bf, pooled, gcnt);
    head_k   <<<1, 128, 0, stream>>>(pooled, gcnt, fcw, fcb, out);
}

// Round 7
// 385.481 us; speedup vs baseline: 2.1702x; 1.1451x over previous
//
#include <hip/hip_runtime.h>

#define NN 50000
#define NE 800000
#define NG 128
#define NK 800000          // NN*16 sort keys (node,cell)
#define NB2 3125           // NK/256, NE/256 (both exact)

typedef unsigned int uint;
typedef unsigned short ushort;
typedef __attribute__((ext_vector_type(8))) short short8;
typedef __attribute__((ext_vector_type(4))) float f32x4;

__device__ __forceinline__ float bf2f(ushort u){ union{uint i; float f;} v; v.i=(uint)u<<16; return v.f; }
__device__ __forceinline__ ushort f2bf(float f){ union{float f; uint i;} v; v.f=f; return (ushort)((v.i + 0x7FFFu + ((v.i>>16)&1u))>>16); }

// ---------------- zero scratch re-initialized every call ----------------
__global__ void zero_k(int* hist2, float* pooled, int* gcnt){
    int i = blockIdx.x*blockDim.x + threadIdx.x;
    if (i < NK) hist2[i] = 0;
    if (i < NG*64) pooled[i] = 0.f;
    if (i < NG) gcnt[i] = 0;
}

// ---------------- (dst,cell) histogram ----------------
__global__ void hist_k(const int* __restrict__ ei, const float* __restrict__ pseudo, int* __restrict__ hist2){
    int e = blockIdx.x*blockDim.x + threadIdx.x;
    if (e >= NE) return;
    float2 ps = *(const float2*)(pseudo + 2*(size_t)e);
    int lx = min(max((int)floorf(ps.x*4.0f), 0), 3);
    int ly = min(max((int)floorf(ps.y*4.0f), 0), 3);
    atomicAdd(&hist2[ei[NE + e]*16 + ly*4 + lx], 1);
}

// ---------------- hierarchical exclusive scan over NK keys ----------------
__global__ __launch_bounds__(256) void scan1(const int* __restrict__ hist2, int* __restrict__ bsum){
    __shared__ int sm[256];
    int t = threadIdx.x, i = blockIdx.x*256 + t;
    sm[t] = (i < NK) ? hist2[i] : 0;
    __syncthreads();
    for (int o = 128; o > 0; o >>= 1){ if (t < o) sm[t] += sm[t+o]; __syncthreads(); }
    if (t == 0) bsum[blockIdx.x] = sm[0];
}
__global__ __launch_bounds__(1024) void scan2(const int* __restrict__ bsum, int* __restrict__ bpre){
    __shared__ int sm[1024];
    int t = threadIdx.x;
    const int CH = (NB2 + 1023)/1024;     // 4
    int base = t*CH, lim = min(base+CH, NB2);
    int s = 0;
    for (int i = base; i < lim; ++i) s += bsum[i];
    sm[t] = s; __syncthreads();
    int acc = s;
    for (int o = 1; o < 1024; o <<= 1){
        int u = (t >= o) ? sm[t-o] : 0; __syncthreads();
        acc += u; sm[t] = acc; __syncthreads();
    }
    int run = acc - s;
    for (int i = base; i < lim; ++i){ bpre[i] = run; run += bsum[i]; }
}
__global__ __launch_bounds__(256) void scan3(const int* __restrict__ hist2, const int* __restrict__ bpre,
                                             int* __restrict__ offs2k, int* __restrict__ cursor){
    __shared__ int sm[256];
    int t = threadIdx.x, b = blockIdx.x, i = b*256 + t;
    int v = (i < NK) ? hist2[i] : 0;
    sm[t] = v; __syncthreads();
    int acc = v;
    for (int o = 1; o < 256; o <<= 1){
        int u = (t >= o) ? sm[t-o] : 0; __syncthreads();
        acc += u; sm[t] = acc; __syncthreads();
    }
    int excl = acc - v + bpre[b];
    if (i < NK){ offs2k[i] = excl; cursor[i] = excl; }
    if (i == NK-1) offs2k[NK] = NE;
}
__global__ __launch_bounds__(256) void invc_k(const int* __restrict__ offs2k, float* __restrict__ invc){
    int n = blockIdx.x*blockDim.x + threadIdx.x;
    if (n < NN) invc[n] = 1.0f / (float)max(offs2k[n*16+16] - offs2k[n*16], 1);
}

// ---------------- counting sort by (dst,cell): payload[pos] = {src|lx|ly, fx, fy} ----------------
__global__ void scatter_k(const int* __restrict__ ei, const float* __restrict__ pseudo,
                          int* __restrict__ cursor, uint4* __restrict__ payload){
    int e = blockIdx.x*blockDim.x + threadIdx.x;
    if (e >= NE) return;
    float2 ps = *(const float2*)(pseudo + 2*(size_t)e);
    float px = ps.x * 4.0f, py = ps.y * 4.0f;
    int lx = min(max((int)floorf(px), 0), 3);
    int ly = min(max((int)floorf(py), 0), 3);
    float fx = px - (float)lx, fy = py - (float)ly;
    uint meta = (uint)ei[e] | ((uint)lx<<16) | ((uint)ly<<18);   // src < 65536
    int key = ei[NE + e]*16 + ly*4 + lx;
    int pos = atomicAdd(&cursor[key], 1);
    payload[pos] = make_uint4(meta, __float_as_uint(fx), __float_as_uint(fy), 0u);
}

// ---------------- pack [Wflat;root] into MFMA B-fragment layout, bf16 ----------------
// Bp[(kt*4+ct)*512 + lane*8 + j] = Bmat[kt*32 + (lane>>4)*8 + j][ct*16 + (lane&15)]
template<int IN>
__global__ void wprep_k(const float* __restrict__ W, const float* __restrict__ root, ushort* __restrict__ Bp){
    const int total = 26*IN*64;
    int tid = blockIdx.x*blockDim.x + threadIdx.x;
    if (tid >= total) return;
    int j    = tid & 7;
    int lane = (tid >> 3) & 63;
    int ctkt = tid >> 9;
    int ct   = ctkt & 3;
    int kt   = ctkt >> 2;
    int kk   = kt*32 + (lane>>4)*8 + j;
    int col  = ct*16 + (lane & 15);
    float v;
    if (kk < 25*IN){ int k = kk / IN; int i = kk % IN; v = W[((size_t)k*IN + i)*64 + col]; }
    else           { v = root[(size_t)(kk - 25*IN)*64 + col]; }
    Bp[tid] = f2bf(v);
}

// ---------------- layer 1: CSR reduce with tiny W1 in LDS (in=1, out=32) ----------------
__global__ __launch_bounds__(256) void reduce1_k(const float* __restrict__ x, const uint4* __restrict__ payload,
                                                 const int* __restrict__ offs2k, const float* __restrict__ invc,
                                                 const float* __restrict__ W1, const float* __restrict__ root1,
                                                 const float* __restrict__ b1, ushort* __restrict__ h1bf){
    __shared__ float w1s[25*32];
    for (int i = threadIdx.x; i < 25*32; i += 256) w1s[i] = W1[i];
    __syncthreads();
    int wid  = threadIdx.x >> 6;
    int lane = threadIdx.x & 63;
    int o    = lane & 31;
    int half = lane >> 5;
    int d    = blockIdx.x*4 + wid;
    int s = offs2k[d*16], e = offs2k[d*16+16];
    float acc = 0.f;
#define EDGE1(PL, XS) { uint meta = (PL).x; \
    int lx = (meta>>16)&3, ly = (meta>>18)&3; \
    float fx = __uint_as_float((PL).y), fy = __uint_as_float((PL).z); \
    float gx = 1.f - fx, gy = 1.f - fy; \
    int ka = ly*5 + lx + half; \
    float wa = half ? fx*gy : gx*gy; \
    float wb = half ? fx*fy : gx*fy; \
    acc += (wa*w1s[ka*32 + o] + wb*w1s[(ka+5)*32 + o]) * (XS); }
    int p = s;
    for (; p + 2 <= e; p += 2){
        uint4 A0 = payload[p], A1 = payload[p+1];
        float x0 = x[A0.x & 0xFFFF];
        float x1 = x[A1.x & 0xFFFF];
        EDGE1(A0, x0) EDGE1(A1, x1)
    }
    if (p < e){
        uint4 A0 = payload[p];
        float x0 = x[A0.x & 0xFFFF];
        EDGE1(A0, x0)
    }
#undef EDGE1
    acc += __shfl_xor(acc, 32);
    if (half == 0){
        float val = acc*invc[d] + x[d]*root1[o] + b1[o];
        val = val > 0.f ? val : expm1f(val);
        h1bf[(size_t)d*32 + o] = f2bf(val);
    }
}

// ---------------- fused layer, cell-bucketed register accumulation ----------------
// 512 threads = 8 waves. IN=64: 1 node/wave (8/block). IN=32: 2 nodes/wave via halves (16/block).
// Edges sorted by (node,cell): per cell the 4 touched S-slots are compile-time -> 4 static FMAs/edge.
template<int IN, int MODE>
__global__ __launch_bounds__(512, 1) void fused_bkt(
        const ushort* __restrict__ hin, const uint4* __restrict__ payload,
        const int* __restrict__ offs2k, const float* __restrict__ invc,
        const ushort* __restrict__ Bp, const float* __restrict__ bias,
        const int* __restrict__ batch, ushort* __restrict__ hout,
        float* __restrict__ pooled, int* __restrict__ gcnt)
{
    constexpr int NND = (IN == 64) ? 8 : 16;
    constexpr int KT  = 26*IN/32, KH = KT/2;
    constexpr int SW  = 26*IN + 8;
    __shared__ __align__(16) ushort Sb[NND*SW];
    __shared__ float red[1024];
    __shared__ float outS[NND*64];

    int tid = threadIdx.x, lane = tid & 63, w = tid >> 6;
    int d0 = blockIdx.x * NND;
    int hnode = (IN == 64) ? w : (w*2 + (lane >> 5));
    int li    = (IN == 64) ? lane : (lane & 31);
    int dd = d0 + hnode;

    // each lane holds one section bound for its node; sections fetch via shfl
    int bl  = (IN == 64) ? min(lane, 16) : min(lane & 31, 16);
    int bnd = offs2k[dd*16 + bl];

    float acc[25];
    #pragma unroll
    for (int k = 0; k < 25; ++k) acc[k] = 0.f;

#define CELLSEC(LX,LY) { \
    constexpr int C = (LY)*4 + (LX); \
    constexpr int B = (LY)*5 + (LX); \
    int p  = (IN == 64) ? __shfl(bnd, C)   : __shfl(bnd, (lane & 32) + C); \
    int pe = (IN == 64) ? __shfl(bnd, C+1) : __shfl(bnd, (lane & 32) + C + 1); \
    for (; p < pe; ++p){ \
        uint4 pl = payload[p]; \
        float fx = __uint_as_float(pl.y), fy = __uint_as_float(pl.z); \
        float xs = bf2f(hin[(size_t)(pl.x & 0xFFFF)*IN + li]); \
        float t0 = (1.f - fx)*xs, t1 = fx*xs, gy = 1.f - fy; \
        acc[B]   = fmaf(gy, t0, acc[B]); \
        acc[B+1] = fmaf(gy, t1, acc[B+1]); \
        acc[B+5] = fmaf(fy, t0, acc[B+5]); \
        acc[B+6] = fmaf(fy, t1, acc[B+6]); \
    } }
    CELLSEC(0,0) CELLSEC(1,0) CELLSEC(2,0) CELLSEC(3,0)
    CELLSEC(0,1) CELLSEC(1,1) CELLSEC(2,1) CELLSEC(3,1)
    CELLSEC(0,2) CELLSEC(1,2) CELLSEC(2,2) CELLSEC(3,2)
    CELLSEC(0,3) CELLSEC(1,3) CELLSEC(2,3) CELLSEC(3,3)
#undef CELLSEC

    // ---- write bf16 A-tile row (both halves own distinct nodes -> all lanes write) ----
    {
        float ic = invc[dd];
        #pragma unroll
        for (int k = 0; k < 25; ++k) Sb[hnode*SW + k*IN + li] = f2bf(acc[k]*ic);
        Sb[hnode*SW + 25*IN + li] = hin[(size_t)dd*IN + li];
    }
    __syncthreads();

    // ---- GEMM: 8 waves = 4 col-tiles x 2 K-halves ----
    int ct = w & 3, kh = w >> 2;
    int row = lane & 15;
    int nodeg = (NND == 16) ? row : (row & 7);
    int cg = (lane >> 4)*8;
    f32x4 a4 = {0.f,0.f,0.f,0.f};
    {
        const ushort* ab = Sb + nodeg*SW + cg;
        const ushort* bb = Bp + ct*512 + (size_t)lane*8;
        #pragma unroll
        for (int k = 0; k < KH; ++k){
            int kt = kh*KH + k;
            short8 a = *(const short8*)(ab + kt*32);
            short8 b = *(const short8*)(bb + (size_t)kt*2048);
            a4 = __builtin_amdgcn_mfma_f32_16x16x32_bf16(a, b, a4, 0, 0, 0);
        }
    }
    if (kh == 1){
        float* r = red + (ct*64 + lane)*4;
        r[0]=a4[0]; r[1]=a4[1]; r[2]=a4[2]; r[3]=a4[3];
    }
    __syncthreads();
    if (kh == 0){
        const float* r = red + (ct*64 + lane)*4;
        int col = ct*16 + (lane & 15);
        float bs = bias[col];
        #pragma unroll
        for (int j = 0; j < 4; ++j){
            int rr = (lane >> 4)*4 + j;
            if (NND == 16 || rr < 8){
                float v = a4[j] + r[j] + bs;
                v = v > 0.f ? v : expm1f(v);
                if (MODE == 0) ((ushort*)outS)[rr*64 + col] = f2bf(v);
                else           outS[rr*64 + col] = v;
            }
        }
    }
    __syncthreads();

    // ---- output ----
    if (MODE == 0){
        uint* dst = (uint*)(hout + (size_t)d0*64);
        const uint* srcp = (const uint*)outS;
        for (int i = tid; i < NND*32; i += 512) dst[i] = srcp[i];
    } else {
        if (w == 0){
            int c = lane;
            float run = 0.f; int gprev = batch[d0];
            for (int r = 0; r < NND; ++r){
                int g = batch[d0 + r];
                if (g != gprev){ atomicAdd(&pooled[gprev*64 + c], run); run = 0.f; gprev = g; }
                run += outS[r*64 + c];
            }
            atomicAdd(&pooled[gprev*64 + c], run);
        } else if (w == 1 && lane == 0){
            int cnt = 0; int gprev = batch[d0];
            for (int r = 0; r < NND; ++r){
                int g = batch[d0 + r];
                if (g != gprev){ atomicAdd(&gcnt[gprev], cnt); cnt = 0; gprev = g; }
                cnt++;
            }
            atomicAdd(&gcnt[gprev], cnt);
        }
    }
}

// ---------------- head: graph mean-pool -> fc -> log_softmax ----------------
__global__ __launch_bounds__(128) void head_k(const float* __restrict__ pooled, const int* __restrict__ gcnt,
                                              const float* __restrict__ fcw, const float* __restrict__ fcb,
                                              float* __restrict__ out){
    int g = threadIdx.x;
    if (g >= NG) return;
    float inv = 1.0f / fmaxf((float)gcnt[g], 1.0f);
    float logits[10];
    #pragma unroll
    for (int c = 0; c < 10; ++c) logits[c] = fcb[c];
    for (int o = 0; o < 64; ++o){
        float m = pooled[g*64 + o] * inv;
        #pragma unroll
        for (int c = 0; c < 10; ++c) logits[c] += m * fcw[o*10 + c];
    }
    float mx = logits[0];
    #pragma unroll
    for (int c = 1; c < 10; ++c) mx = fmaxf(mx, logits[c]);
    float ssum = 0.f;
    #pragma unroll
    for (int c = 0; c < 10; ++c) ssum += expf(logits[c] - mx);
    float lse = logf(ssum) + mx;
    #pragma unroll
    for (int c = 0; c < 10; ++c) out[g*10 + c] = logits[c] - lse;
}

extern "C" void kernel_launch(void* const* d_in, const int* in_sizes, int n_in,
                              void* d_out, int out_size, void* d_ws, size_t ws_size,
                              hipStream_t stream) {
    const float* x      = (const float*)d_in[0];
    const float* pseudo = (const float*)d_in[2];
    const int*   ei     = (const int*)  d_in[3];
    const int*   batch  = (const int*)  d_in[4];
    const float* W1     = (const float*)d_in[5];
    const float* root1  = (const float*)d_in[6];
    const float* b1     = (const float*)d_in[7];
    const float* W2     = (const float*)d_in[8];
    const float* root2  = (const float*)d_in[9];
    const float* b2     = (const float*)d_in[10];
    const float* W3     = (const float*)d_in[11];
    const float* root3  = (const float*)d_in[12];
    const float* b3     = (const float*)d_in[13];
    const float* fcw    = (const float*)d_in[14];
    const float* fcb    = (const float*)d_in[15];
    float* out = (float*)d_out;

    char* ws = (char*)d_ws;
    size_t off = 0;
    auto alloc = [&](size_t bytes)->char*{ char* p = ws + off; off += (bytes + 255) / 256 * 256; return p; };
    uint4*  payload= (uint4*) alloc((size_t)NE*16);
    ushort* h1bf   = (ushort*)alloc((size_t)NN*32*2);
    ushort* h2bf   = (ushort*)alloc((size_t)NN*64*2);
    int*    hist2  = (int*)   alloc((size_t)NK*4);
    int*    offs2k = (int*)   alloc((size_t)(NK+1)*4);
    int*    cursor = (int*)   alloc((size_t)NK*4);
    float*  invc   = (float*) alloc((size_t)NN*4);
    int*    bsum   = (int*)   alloc((size_t)NB2*4);
    int*    bpre   = (int*)   alloc((size_t)NB2*4);
    ushort* Bp2    = (ushort*)alloc((size_t)26*2048*2);
    ushort* Bp3    = (ushort*)alloc((size_t)52*2048*2);
    float*  pooled = (float*) alloc((size_t)NG*64*4);
    int*    gcnt   = (int*)   alloc((size_t)NG*4);
    (void)ws_size; (void)in_sizes; (void)n_in; (void)out_size;

    zero_k   <<<NB2, 256, 0, stream>>>(hist2, pooled, gcnt);
    hist_k   <<<NB2, 256, 0, stream>>>(ei, pseudo, hist2);
    scan1    <<<NB2, 256, 0, stream>>>(hist2, bsum);
    scan2    <<<1, 1024, 0, stream>>>(bsum, bpre);
    scan3    <<<NB2, 256, 0, stream>>>(hist2, bpre, offs2k, cursor);
    invc_k   <<<(NN+255)/256, 256, 0, stream>>>(offs2k, invc);
    scatter_k<<<NB2, 256, 0, stream>>>(ei, pseudo, cursor, payload);
    wprep_k<32><<<(26*32*64 + 255)/256, 256, 0, stream>>>(W2, root2, Bp2);
    wprep_k<64><<<(26*64*64 + 255)/256, 256, 0, stream>>>(W3, root3, Bp3);
    reduce1_k<<<NN/4, 256, 0, stream>>>(x, payload, offs2k, invc, W1, root1, b1, h1bf);
    fused_bkt<32,0><<<NN/16, 512, 0, stream>>>(h1bf, payload, offs2k, invc, Bp2, b2, batch, h2bf, pooled, gcnt);
    fused_bkt<64,1><<<NN/8,  512, 0, stream>>>(h2bf, payload, offs2k, invc, Bp3, b3, batch, h2bf, pooled, gcnt);
    head_k   <<<1, 128, 0, stream>>>(pooled, gcnt, fcw, fcb, out);
}